// Round 13
// baseline (235.788 us; speedup 1.0000x reference)
//
#include <hip/hip_runtime.h>
#include <hip/hip_bf16.h>

typedef __bf16 bf16x8 __attribute__((ext_vector_type(8)));
typedef float f32x4 __attribute__((ext_vector_type(4)));

#define EPS 1e-5f
// 0.125 * log2(e): folded into Q via LN gamma/beta in qkv, so P = exp2(S)
#define QSCALE 0.18033688011112042f

__device__ __forceinline__ unsigned short f2bf(float f) {
  union { float f; unsigned int i; } c; c.f = f;
  unsigned int r = c.i + 0x7FFFu + ((c.i >> 16) & 1u);
  return (unsigned short)(r >> 16);
}

// async global->LDS, 16B per lane; LDS dst = base + lane*16B (wave-uniform base)
#define GLOAD_LDS16(g, s)                                                  \
  __builtin_amdgcn_global_load_lds(                                        \
      (const __attribute__((address_space(1))) unsigned int*)(g),          \
      (__attribute__((address_space(3))) unsigned int*)(s), 16, 0, 0)

// -------- Transpose+convert: in fp32 [R,C] -> out bf16 [C,R], 64x64 tiles --
__global__ __launch_bounds__(256) void transpose_f32_bf16(
    const float* __restrict__ in, unsigned short* __restrict__ out,
    int R, int C)
{
  __shared__ __align__(16) unsigned short S[64 * 72];
  const int t = threadIdx.x;
  const int r = t >> 2, c4 = (t & 3) * 16;
  const int rt0 = blockIdx.y * 64, ct0 = blockIdx.x * 64;

  {
    long base = (long)(rt0 + r) * C + ct0 + c4;
    float4 a = *(const float4*)&in[base];
    float4 b = *(const float4*)&in[base + 4];
    float4 c = *(const float4*)&in[base + 8];
    float4 d = *(const float4*)&in[base + 12];
    unsigned short v[16] = {f2bf(a.x), f2bf(a.y), f2bf(a.z), f2bf(a.w),
                            f2bf(b.x), f2bf(b.y), f2bf(b.z), f2bf(b.w),
                            f2bf(c.x), f2bf(c.y), f2bf(c.z), f2bf(c.w),
                            f2bf(d.x), f2bf(d.y), f2bf(d.z), f2bf(d.w)};
    *(uint4*)&S[r * 72 + c4]     = *(uint4*)&v[0];
    *(uint4*)&S[r * 72 + c4 + 8] = *(uint4*)&v[8];
  }
  __syncthreads();

  unsigned short tmp[16];
#pragma unroll
  for (int j = 0; j < 16; j++) tmp[j] = S[(c4 + j) * 72 + r];
  *(uint4*)&out[(long)(ct0 + r) * R + rt0 + c4]     = *(uint4*)&tmp[0];
  *(uint4*)&out[(long)(ct0 + r) * R + rt0 + c4 + 8] = *(uint4*)&tmp[8];
}

// -------- Flat convert: fp32 -> bf16, 16 elems/thread ----------------------
__global__ __launch_bounds__(256) void convert_f32_bf16(
    const float* __restrict__ in, unsigned short* __restrict__ out)
{
  long i = ((long)blockIdx.x * 256 + threadIdx.x) * 16;
  float4 a = *(const float4*)&in[i];
  float4 b = *(const float4*)&in[i + 4];
  float4 c = *(const float4*)&in[i + 8];
  float4 d = *(const float4*)&in[i + 12];
  unsigned short v[16] = {f2bf(a.x), f2bf(a.y), f2bf(a.z), f2bf(a.w),
                          f2bf(b.x), f2bf(b.y), f2bf(b.z), f2bf(b.w),
                          f2bf(c.x), f2bf(c.y), f2bf(c.z), f2bf(c.w),
                          f2bf(d.x), f2bf(d.y), f2bf(d.z), f2bf(d.w)};
  *(uint4*)&out[i]     = *(uint4*)&v[0];
  *(uint4*)&out[i + 8] = *(uint4*)&v[8];
}

// ---------------- Kernel 1: Q/K GEMM 128x128, dbuf + global_load_lds ------
__global__ __launch_bounds__(256) void qkv_ln_kernel(
    const float* __restrict__ Xf,
    const unsigned short* __restrict__ Xbf, int use_xbf,
    const unsigned short* __restrict__ WT,
    const float* __restrict__ bias,
    const float* __restrict__ qg, const float* __restrict__ qb,
    const float* __restrict__ kg, const float* __restrict__ kb,
    unsigned short* __restrict__ Qws, unsigned short* __restrict__ Kws)
{
  __shared__ __align__(16) unsigned short As[2][128 * 32];
  __shared__ __align__(16) unsigned short Bs[2][128 * 32];

  const int tid = threadIdx.x;
  const int w = tid >> 6, lane = tid & 63, quad = lane >> 4, l15 = lane & 15;
  const int mh = w & 1, nh = w >> 1;
  const int n0 = blockIdx.x * 128, m0 = blockIdx.y * 128;

  f32x4 acc[4][4];
#pragma unroll
  for (int i = 0; i < 4; i++)
#pragma unroll
    for (int j = 0; j < 4; j++) acc[i][j] = (f32x4){0.f, 0.f, 0.f, 0.f};

  const int srow = lane >> 2, soff = (lane & 3) * 8;   // GLOAD lane map
  const int sr2 = tid >> 1, sh2 = (tid & 1) * 16;      // fp32 fallback map

  // prologue: stage kt=0 into buf 0
#pragma unroll
  for (int i = 0; i < 2; i++) {
    const int rr0 = w * 32 + i * 16;
    GLOAD_LDS16(WT + (long)(n0 + rr0 + srow) * 1024 + soff, &Bs[0][rr0 * 32]);
    if (use_xbf)
      GLOAD_LDS16(Xbf + (long)(m0 + rr0 + srow) * 1024 + soff, &As[0][rr0 * 32]);
  }
  if (!use_xbf) {
    long xo = (long)(m0 + sr2) * 1024 + sh2;
    float4 a0 = *(const float4*)&Xf[xo];
    float4 a1 = *(const float4*)&Xf[xo + 4];
    float4 a2 = *(const float4*)&Xf[xo + 8];
    float4 a3 = *(const float4*)&Xf[xo + 12];
    unsigned short v[16] = {f2bf(a0.x), f2bf(a0.y), f2bf(a0.z), f2bf(a0.w),
                            f2bf(a1.x), f2bf(a1.y), f2bf(a1.z), f2bf(a1.w),
                            f2bf(a2.x), f2bf(a2.y), f2bf(a2.z), f2bf(a2.w),
                            f2bf(a3.x), f2bf(a3.y), f2bf(a3.z), f2bf(a3.w)};
    *(uint4*)&As[0][sr2 * 32 + sh2]     = *(uint4*)&v[0];
    *(uint4*)&As[0][sr2 * 32 + sh2 + 8] = *(uint4*)&v[8];
  }
  __syncthreads();

  int buf = 0;
  for (int kt = 0; kt < 1024; kt += 32) {
    const int nbuf = buf ^ 1;
    const bool pf = (kt + 32) < 1024;
    float4 a0, a1, a2, a3;
    if (pf) {
#pragma unroll
      for (int i = 0; i < 2; i++) {
        const int rr0 = w * 32 + i * 16;
        GLOAD_LDS16(WT + (long)(n0 + rr0 + srow) * 1024 + kt + 32 + soff,
                    &Bs[nbuf][rr0 * 32]);
        if (use_xbf)
          GLOAD_LDS16(Xbf + (long)(m0 + rr0 + srow) * 1024 + kt + 32 + soff,
                      &As[nbuf][rr0 * 32]);
      }
      if (!use_xbf) {
        long xo = (long)(m0 + sr2) * 1024 + kt + 32 + sh2;
        a0 = *(const float4*)&Xf[xo];
        a1 = *(const float4*)&Xf[xo + 4];
        a2 = *(const float4*)&Xf[xo + 8];
        a3 = *(const float4*)&Xf[xo + 12];
      }
    }

    bf16x8 af[4], bfr[4];
#pragma unroll
    for (int mq = 0; mq < 4; mq++)
      af[mq] = *(const bf16x8*)&As[buf][(mh * 64 + mq * 16 + l15) * 32 + quad * 8];
#pragma unroll
    for (int nq = 0; nq < 4; nq++)
      bfr[nq] = *(const bf16x8*)&Bs[buf][(nh * 64 + nq * 16 + l15) * 32 + quad * 8];
#pragma unroll
    for (int mq = 0; mq < 4; mq++)
#pragma unroll
      for (int nq = 0; nq < 4; nq++)
        acc[mq][nq] = __builtin_amdgcn_mfma_f32_16x16x32_bf16(af[mq], bfr[nq], acc[mq][nq], 0, 0, 0);

    if (pf && !use_xbf) {
      unsigned short v[16] = {f2bf(a0.x), f2bf(a0.y), f2bf(a0.z), f2bf(a0.w),
                              f2bf(a1.x), f2bf(a1.y), f2bf(a1.z), f2bf(a1.w),
                              f2bf(a2.x), f2bf(a2.y), f2bf(a2.z), f2bf(a2.w),
                              f2bf(a3.x), f2bf(a3.y), f2bf(a3.z), f2bf(a3.w)};
      *(uint4*)&As[nbuf][sr2 * 32 + sh2]     = *(uint4*)&v[0];
      *(uint4*)&As[nbuf][sr2 * 32 + sh2 + 8] = *(uint4*)&v[8];
    }
    __syncthreads();
    buf = nbuf;
  }

#pragma unroll
  for (int nq = 0; nq < 4; nq++) {
    float bv = bias[n0 + nh * 64 + nq * 16 + l15];
#pragma unroll
    for (int mq = 0; mq < 4; mq++)
#pragma unroll
      for (int rr = 0; rr < 4; rr++) acc[mq][nq][rr] += bv;
  }

  const int g = (n0 >> 6) + nh;   // 0..31: Q heads then K heads
  const bool isQ = g < 16;

  {
    float gv[4], bev[4];
#pragma unroll
    for (int nq = 0; nq < 4; nq++) {
      int d = nq * 16 + l15;
      gv[nq]  = isQ ? qg[d] : kg[d];
      bev[nq] = isQ ? qb[d] : kb[d];
      if (isQ) { gv[nq] *= QSCALE; bev[nq] *= QSCALE; }
    }
#pragma unroll
    for (int mq = 0; mq < 4; mq++)
#pragma unroll
      for (int rr = 0; rr < 4; rr++) {
        float s  = acc[mq][0][rr] + acc[mq][1][rr] + acc[mq][2][rr] + acc[mq][3][rr];
        float s2 = acc[mq][0][rr]*acc[mq][0][rr] + acc[mq][1][rr]*acc[mq][1][rr]
                 + acc[mq][2][rr]*acc[mq][2][rr] + acc[mq][3][rr]*acc[mq][3][rr];
#pragma unroll
        for (int off = 1; off < 16; off <<= 1) {
          s  += __shfl_xor(s,  off, 64);
          s2 += __shfl_xor(s2, off, 64);
        }
        float mu   = s * (1.0f / 64.0f);
        float var  = fmaxf(s2 * (1.0f / 64.0f) - mu * mu, 0.f);
        float rstd = rsqrtf(var + EPS);
#pragma unroll
        for (int nq = 0; nq < 4; nq++)
          acc[mq][nq][rr] = (acc[mq][nq][rr] - mu) * rstd * gv[nq] + bev[nq];
      }
  }

  unsigned short* dst = isQ ? Qws : Kws;
  const int head = isQ ? g : g - 16;

#pragma unroll
  for (int mq = 0; mq < 4; mq++)
#pragma unroll
    for (int rr = 0; rr < 4; rr++) {
      int m = m0 + mh * 64 + mq * 16 + quad * 4 + rr;
      int b = m >> 11, s = m & 2047;
      long base = ((long)((b * 16 + head) * 2048 + s)) * 64;
#pragma unroll
      for (int nq = 0; nq < 4; nq++)
        dst[base + nq * 16 + l15] = f2bf(acc[mq][nq][rr]);
    }
}

// ---------------- Kernel 1b: V^T GEMM (Vt[bh][d][s]), dbuf + GLOAD --------
__global__ __launch_bounds__(256) void vt_kernel(
    const float* __restrict__ Xf,
    const unsigned short* __restrict__ Xbf, int use_xbf,
    const unsigned short* __restrict__ WvT,
    const float* __restrict__ bias,           // b_attn; index 2048+m
    unsigned short* __restrict__ Vt)
{
  __shared__ __align__(16) unsigned short As[2][128 * 32];
  __shared__ __align__(16) unsigned short Bs[2][128 * 32];

  const int tid = threadIdx.x;
  const int w = tid >> 6, lane = tid & 63, quad = lane >> 4, l15 = lane & 15;
  const int mh = w & 1, nh = w >> 1;
  const int n0 = blockIdx.x * 128, m0 = blockIdx.y * 128, bz = blockIdx.z;
  const long xrow0 = (long)bz * 2048;

  f32x4 acc[4][4];
#pragma unroll
  for (int i = 0; i < 4; i++)
#pragma unroll
    for (int j = 0; j < 4; j++) acc[i][j] = (f32x4){0.f, 0.f, 0.f, 0.f};

  const int srow = lane >> 2, soff = (lane & 3) * 8;
  const int sr2 = tid >> 1, sh2 = (tid & 1) * 16;

#pragma unroll
  for (int i = 0; i < 2; i++) {
    const int rr0 = w * 32 + i * 16;
    GLOAD_LDS16(WvT + (long)(m0 + rr0 + srow) * 1024 + soff, &As[0][rr0 * 32]);
    if (use_xbf)
      GLOAD_LDS16(Xbf + (xrow0 + n0 + rr0 + srow) * 1024 + soff, &Bs[0][rr0 * 32]);
  }
  if (!use_xbf) {
    long xo = (xrow0 + n0 + sr2) * 1024 + sh2;
    float4 a0 = *(const float4*)&Xf[xo];
    float4 a1 = *(const float4*)&Xf[xo + 4];
    float4 a2 = *(const float4*)&Xf[xo + 8];
    float4 a3 = *(const float4*)&Xf[xo + 12];
    unsigned short v[16] = {f2bf(a0.x), f2bf(a0.y), f2bf(a0.z), f2bf(a0.w),
                            f2bf(a1.x), f2bf(a1.y), f2bf(a1.z), f2bf(a1.w),
                            f2bf(a2.x), f2bf(a2.y), f2bf(a2.z), f2bf(a2.w),
                            f2bf(a3.x), f2bf(a3.y), f2bf(a3.z), f2bf(a3.w)};
    *(uint4*)&Bs[0][sr2 * 32 + sh2]     = *(uint4*)&v[0];
    *(uint4*)&Bs[0][sr2 * 32 + sh2 + 8] = *(uint4*)&v[8];
  }
  __syncthreads();

  int buf = 0;
  for (int kt = 0; kt < 1024; kt += 32) {
    const int nbuf = buf ^ 1;
    const bool pf = (kt + 32) < 1024;
    float4 a0, a1, a2, a3;
    if (pf) {
#pragma unroll
      for (int i = 0; i < 2; i++) {
        const int rr0 = w * 32 + i * 16;
        GLOAD_LDS16(WvT + (long)(m0 + rr0 + srow) * 1024 + kt + 32 + soff,
                    &As[nbuf][rr0 * 32]);
        if (use_xbf)
          GLOAD_LDS16(Xbf + (xrow0 + n0 + rr0 + srow) * 1024 + kt + 32 + soff,
                      &Bs[nbuf][rr0 * 32]);
      }
      if (!use_xbf) {
        long xo = (xrow0 + n0 + sr2) * 1024 + kt + 32 + sh2;
        a0 = *(const float4*)&Xf[xo];
        a1 = *(const float4*)&Xf[xo + 4];
        a2 = *(const float4*)&Xf[xo + 8];
        a3 = *(const float4*)&Xf[xo + 12];
      }
    }

    bf16x8 af[4], bfr[4];
#pragma unroll
    for (int mq = 0; mq < 4; mq++)
      af[mq] = *(const bf16x8*)&As[buf][(mh * 64 + mq * 16 + l15) * 32 + quad * 8];
#pragma unroll
    for (int nq = 0; nq < 4; nq++)
      bfr[nq] = *(const bf16x8*)&Bs[buf][(nh * 64 + nq * 16 + l15) * 32 + quad * 8];
#pragma unroll
    for (int mq = 0; mq < 4; mq++)
#pragma unroll
      for (int nq = 0; nq < 4; nq++)
        acc[mq][nq] = __builtin_amdgcn_mfma_f32_16x16x32_bf16(af[mq], bfr[nq], acc[mq][nq], 0, 0, 0);

    if (pf && !use_xbf) {
      unsigned short v[16] = {f2bf(a0.x), f2bf(a0.y), f2bf(a0.z), f2bf(a0.w),
                              f2bf(a1.x), f2bf(a1.y), f2bf(a1.z), f2bf(a1.w),
                              f2bf(a2.x), f2bf(a2.y), f2bf(a2.z), f2bf(a2.w),
                              f2bf(a3.x), f2bf(a3.y), f2bf(a3.z), f2bf(a3.w)};
      *(uint4*)&Bs[nbuf][sr2 * 32 + sh2]     = *(uint4*)&v[0];
      *(uint4*)&Bs[nbuf][sr2 * 32 + sh2 + 8] = *(uint4*)&v[8];
    }
    __syncthreads();
    buf = nbuf;
  }

  const long outb = (long)bz * 2097152;
#pragma unroll
  for (int mq = 0; mq < 4; mq++)
#pragma unroll
    for (int rr = 0; rr < 4; rr++) {
      int m = m0 + mh * 64 + mq * 16 + quad * 4 + rr;
      float bv = bias[2048 + m];
#pragma unroll
      for (int nq = 0; nq < 4; nq++) {
        int n = n0 + nh * 64 + nq * 16 + l15;
        Vt[outb + (long)m * 2048 + n] = f2bf(acc[mq][nq][rr] + bv);
      }
    }
}

// ---------------- Kernel 2: causal attention, 128-row Q, 34KB LDS ---------
// 512 blocks fully resident; pair remap -> constant 34 iter-units per CU.
// K/VT single-buffered stride-72 (conflict-free b128); Q staged with the
// P-read XOR swizzle (kills prologue conflicts); Ps rows wave-private.
__global__ __launch_bounds__(256) void attn_kernel(
    unsigned short* __restrict__ Qws,        // in: Q (pre-scaled), out: O
    const unsigned short* __restrict__ Kws,
    const unsigned short* __restrict__ Vt)
{
  __shared__ __align__(16) unsigned short Ks[64 * 72];
  __shared__ __align__(16) unsigned short VTs[64 * 72];  // [d][s-kb]
  __shared__ __align__(16) unsigned short Ps[128 * 64];  // swizzled; Q staging

  const int tid = threadIdx.x;
  const int w = tid >> 6, lane = tid & 63, quad = lane >> 4, l15 = lane & 15;
  const int bh = blockIdx.y;
  const int qt2 = (bh < 16) ? (15 - blockIdx.x) : blockIdx.x;  // pair-balance
  const int qbase = qt2 * 128;
  const long bhoff = (long)bh * 2048 * 64;
  const long bhv   = (long)bh * 131072;      // 64*2048
  const int jmax = 2 * qt2 + 2;

  const int sr = tid >> 2, sc = (tid & 3) * 16;   // K/VT staging map
  const int qr = tid >> 1, qc = (tid & 1) * 32;   // Q staging map
  const int qsw = ((qr >> 2) & 3) << 4;

  // stage Q swizzled (wave w stages rows w*32..w*32+31 — wave-private)
#pragma unroll
  for (int c = 0; c < 32; c += 8)
    *(uint4*)&Ps[qr * 64 + (((qc + c) ^ qsw))] =
        *(const uint4*)&Qws[bhoff + (qbase + qr) * 64 + qc + c];
  // stage K/VT tile j=0
  *(uint4*)&Ks[sr * 72 + sc]      = *(const uint4*)&Kws[bhoff + sr * 64 + sc];
  *(uint4*)&Ks[sr * 72 + sc + 8]  = *(const uint4*)&Kws[bhoff + sr * 64 + sc + 8];
  *(uint4*)&VTs[sr * 72 + sc]     = *(const uint4*)&Vt[bhv + sr * 2048 + sc];
  *(uint4*)&VTs[sr * 72 + sc + 8] = *(const uint4*)&Vt[bhv + sr * 2048 + sc + 8];
  __syncthreads();

  const int sw = ((l15 >> 2) & 3) << 4;
  const int pc0 = (quad * 8) ^ sw;
  const int pc1 = (32 + quad * 8) ^ sw;

  bf16x8 qf[2][2];
#pragma unroll
  for (int mq = 0; mq < 2; mq++) {
    qf[mq][0] = *(const bf16x8*)&Ps[(w * 32 + mq * 16 + l15) * 64 + pc0];
    qf[mq][1] = *(const bf16x8*)&Ps[(w * 32 + mq * 16 + l15) * 64 + pc1];
  }
  // no barrier: Ps rows wave-private for Q reads and P writes

  bf16x8 ones;
  {
    union { unsigned short u[8]; bf16x8 v; } c;
#pragma unroll
    for (int i = 0; i < 8; i++) c.u[i] = 0x3F80u;
    ones = c.v;
  }

  f32x4 o[2][4], osum[2];
#pragma unroll
  for (int mq = 0; mq < 2; mq++) {
#pragma unroll
    for (int i = 0; i < 4; i++) o[mq][i] = (f32x4){0.f, 0.f, 0.f, 0.f};
    osum[mq] = (f32x4){0.f, 0.f, 0.f, 0.f};
  }

  for (int j = 0; j < jmax; j++) {
    const int kb = j * 64;
    const bool pf = (j + 1) < jmax;
    uint4 pk0, pk1, pv0, pv1;
    if (pf) {
      const int kb1 = kb + 64;
      pk0 = *(const uint4*)&Kws[bhoff + (kb1 + sr) * 64 + sc];
      pk1 = *(const uint4*)&Kws[bhoff + (kb1 + sr) * 64 + sc + 8];
      pv0 = *(const uint4*)&Vt[bhv + sr * 2048 + kb1 + sc];
      pv1 = *(const uint4*)&Vt[bhv + sr * 2048 + kb1 + sc + 8];
    }

    // S = Q K^T
    f32x4 sacc[2][4];
#pragma unroll
    for (int mq = 0; mq < 2; mq++)
#pragma unroll
      for (int i = 0; i < 4; i++) sacc[mq][i] = (f32x4){0.f, 0.f, 0.f, 0.f};
#pragma unroll
    for (int nt = 0; nt < 4; nt++) {
      bf16x8 kf0 = *(const bf16x8*)&Ks[(nt * 16 + l15) * 72 + quad * 8];
      bf16x8 kf1 = *(const bf16x8*)&Ks[(nt * 16 + l15) * 72 + 32 + quad * 8];
#pragma unroll
      for (int mq = 0; mq < 2; mq++) {
        sacc[mq][nt] = __builtin_amdgcn_mfma_f32_16x16x32_bf16(qf[mq][0], kf0, sacc[mq][nt], 0, 0, 0);
        sacc[mq][nt] = __builtin_amdgcn_mfma_f32_16x16x32_bf16(qf[mq][1], kf1, sacc[mq][nt], 0, 0, 0);
      }
    }

    // P = exp2(S); masked -> 0 (scale folded upstream; |S| <= 11.6)
    const bool domask = (j >= 2 * qt2);
#pragma unroll
    for (int mq = 0; mq < 2; mq++)
#pragma unroll
      for (int nt = 0; nt < 4; nt++)
#pragma unroll
        for (int rr = 0; rr < 4; rr++) {
          float p = exp2f(sacc[mq][nt][rr]);
          if (domask) {
            int kcol = kb + nt * 16 + l15;
            int qrow = qbase + w * 32 + mq * 16 + quad * 4 + rr;
            if (kcol > qrow) p = 0.f;
          }
          sacc[mq][nt][rr] = p;
        }

    // P: C-layout -> LDS (own rows), XOR swizzle
#pragma unroll
    for (int mq = 0; mq < 2; mq++)
#pragma unroll
      for (int rr = 0; rr < 4; rr++)
#pragma unroll
        for (int nt = 0; nt < 4; nt++)
          Ps[(w * 32 + mq * 16 + quad * 4 + rr) * 64 + (((nt ^ quad) & 3) * 16 + l15)]
              = f2bf(sacc[mq][nt][rr]);

    bf16x8 pfr[2][2];
#pragma unroll
    for (int mq = 0; mq < 2; mq++) {
      pfr[mq][0] = *(const bf16x8*)&Ps[(w * 32 + mq * 16 + l15) * 64 + pc0];
      pfr[mq][1] = *(const bf16x8*)&Ps[(w * 32 + mq * 16 + l15) * 64 + pc1];
    }

#pragma unroll
    for (int mq = 0; mq < 2; mq++) {
      osum[mq] = __builtin_amdgcn_mfma_f32_16x16x32_bf16(pfr[mq][0], ones, osum[mq], 0, 0, 0);
      osum[mq] = __builtin_amdgcn_mfma_f32_16x16x32_bf16(pfr[mq][1], ones, osum[mq], 0, 0, 0);
    }
#pragma unroll
    for (int dt = 0; dt < 4; dt++) {
      bf16x8 vf0 = *(const bf16x8*)&VTs[(dt * 16 + l15) * 72 + quad * 8];
      bf16x8 vf1 = *(const bf16x8*)&VTs[(dt * 16 + l15) * 72 + 32 + quad * 8];
#pragma unroll
      for (int mq = 0; mq < 2; mq++) {
        o[mq][dt] = __builtin_amdgcn_mfma_f32_16x16x32_bf16(pfr[mq][0], vf0, o[mq][dt], 0, 0, 0);
        o[mq][dt] = __builtin_amdgcn_mfma_f32_16x16x32_bf16(pfr[mq][1], vf1, o[mq][dt], 0, 0, 0);
      }
    }

    if (pf) {
      __syncthreads();   // all waves done reading Ks/VTs
      *(uint4*)&Ks[sr * 72 + sc]      = pk0;
      *(uint4*)&Ks[sr * 72 + sc + 8]  = pk1;
      *(uint4*)&VTs[sr * 72 + sc]     = pv0;
      *(uint4*)&VTs[sr * 72 + sc + 8] = pv1;
      __syncthreads();   // staging visible
    }
  }

  // write O in-place over this block's Q rows
#pragma unroll
  for (int mq = 0; mq < 2; mq++)
#pragma unroll
    for (int rr = 0; rr < 4; rr++) {
      float inv = 1.0f / osum[mq][rr];
      int row = qbase + w * 32 + mq * 16 + quad * 4 + rr;
      long base = bhoff + (long)row * 64;
#pragma unroll
      for (int dt = 0; dt < 4; dt++)
        Qws[base + dt * 16 + l15] = f2bf(o[mq][dt][rr] * inv);
    }
}

// ---------------- Kernel 3: output projection 128x128, dbuf + GLOAD -------
__global__ __launch_bounds__(256) void proj_kernel(
    const unsigned short* __restrict__ AQ,
    const unsigned short* __restrict__ WT,
    const float* __restrict__ bias,
    float* __restrict__ Out)
{
  __shared__ __align__(16) unsigned short As[2][128 * 32];
  __shared__ __align__(16) unsigned short Bs[2][128 * 32];

  const int tid = threadIdx.x;
  const int w = tid >> 6, lane = tid & 63, quad = lane >> 4, l15 = lane & 15;
  const int mh = w & 1, nh = w >> 1;
  const int n0 = blockIdx.x * 128, m0 = blockIdx.y * 128;

  f32x4 acc[4][4];
#pragma unroll
  for (int i = 0; i < 4; i++)
#pragma unroll
    for (int j = 0; j < 4; j++) acc[i][j] = (f32x4){0.f, 0.f, 0.f, 0.f};

  const int srow = lane >> 2, soff = (lane & 3) * 8;

  // prologue kt=0: A from blocked layout (32-k slab stays within one head)
#pragma unroll
  for (int i = 0; i < 2; i++) {
    const int rr0 = w * 32 + i * 16;
    const int m = m0 + rr0 + srow, b = m >> 11, s = m & 2047;
    GLOAD_LDS16(AQ + ((long)(b * 16) * 2048 + s) * 64 + soff, &As[0][rr0 * 32]);
    GLOAD_LDS16(WT + (long)(n0 + rr0 + srow) * 1024 + soff, &Bs[0][rr0 * 32]);
  }
  __syncthreads();

  int buf = 0;
  for (int kt = 0; kt < 1024; kt += 32) {
    const int nbuf = buf ^ 1;
    const bool pf = (kt + 32) < 1024;
    if (pf) {
      const int k = kt + 32, h = k >> 6, d0 = k & 63;
#pragma unroll
      for (int i = 0; i < 2; i++) {
        const int rr0 = w * 32 + i * 16;
        const int m = m0 + rr0 + srow, b = m >> 11, s = m & 2047;
        GLOAD_LDS16(AQ + ((long)((b * 16 + h) * 2048) + s) * 64 + d0 + soff,
                    &As[nbuf][rr0 * 32]);
        GLOAD_LDS16(WT + (long)(n0 + rr0 + srow) * 1024 + k + soff,
                    &Bs[nbuf][rr0 * 32]);
      }
    }

    bf16x8 af[4], bfr[4];
#pragma unroll
    for (int mq = 0; mq < 4; mq++)
      af[mq] = *(const bf16x8*)&As[buf][(mh * 64 + mq * 16 + l15) * 32 + quad * 8];
#pragma unroll
    for (int nq = 0; nq < 4; nq++)
      bfr[nq] = *(const bf16x8*)&Bs[buf][(nh * 64 + nq * 16 + l15) * 32 + quad * 8];
#pragma unroll
    for (int mq = 0; mq < 4; mq++)
#pragma unroll
      for (int nq = 0; nq < 4; nq++)
        acc[mq][nq] = __builtin_amdgcn_mfma_f32_16x16x32_bf16(af[mq], bfr[nq], acc[mq][nq], 0, 0, 0);
    __syncthreads();
    buf = nbuf;
  }

#pragma unroll
  for (int nq = 0; nq < 4; nq++) {
    int n = n0 + nh * 64 + nq * 16 + l15;
    float bv = bias[n];
#pragma unroll
    for (int mq = 0; mq < 4; mq++)
#pragma unroll
      for (int rr = 0; rr < 4; rr++) {
        int mm = m0 + mh * 64 + mq * 16 + quad * 4 + rr;
        Out[(long)mm * 1024 + n] = acc[mq][nq][rr] + bv;
      }
  }
}

extern "C" void kernel_launch(void* const* d_in, const int* in_sizes, int n_in,
                              void* d_out, int out_size, void* d_ws, size_t ws_size,
                              hipStream_t stream) {
  const float* X  = (const float*)d_in[0];
  const float* Wa = (const float*)d_in[1];
  const float* ba = (const float*)d_in[2];
  const float* Wp = (const float*)d_in[3];
  const float* bp = (const float*)d_in[4];
  const float* qg = (const float*)d_in[5];
  const float* qb = (const float*)d_in[6];
  const float* kg = (const float*)d_in[7];
  const float* kb = (const float*)d_in[8];

  const long per = 2L * 16 * 2048 * 64;     // 4,194,304 shorts
  unsigned short* ws  = (unsigned short*)d_ws;
  unsigned short* Qws = ws;
  unsigned short* Kws = Qws + per;
  unsigned short* Vt  = Kws + per;          // [bh][64 d][2048 s]

  const bool big = ws_size >= (size_t)(5L * per * 2);
  unsigned short *Xbf, *WaT, *WpT;
  if (big) {
    Xbf = Vt + per;
    WaT = Xbf + per;
    WpT = WaT + 3072L * 1024;
  } else {
    Xbf = Qws;  // unused
    WaT = Vt + per;
    WpT = WaT + 3072L * 1024;
  }
  unsigned short* WvT = WaT + 2048L * 1024;   // V rows of WaT

  transpose_f32_bf16<<<dim3(48, 16), 256, 0, stream>>>(Wa, WaT, 1024, 3072);
  transpose_f32_bf16<<<dim3(16, 16), 256, 0, stream>>>(Wp, WpT, 1024, 1024);
  if (big) convert_f32_bf16<<<1024, 256, 0, stream>>>(X, Xbf);
  qkv_ln_kernel<<<dim3(16, 32), 256, 0, stream>>>(X, Xbf, big ? 1 : 0, WaT, ba,
                                                  qg, qb, kg, kb, Qws, Kws);
  vt_kernel<<<dim3(16, 8, 2), 256, 0, stream>>>(X, Xbf, big ? 1 : 0, WvT, ba, Vt);
  attn_kernel<<<dim3(16, 32), 256, 0, stream>>>(Qws, Kws, Vt);
  proj_kernel<<<dim3(8, 32), 256, 0, stream>>>(Qws, WpT, bp, (float*)d_out);
}

// Round 14
// 221.819 us; speedup vs baseline: 1.0630x; 1.0630x over previous
//
#include <hip/hip_runtime.h>
#include <hip/hip_bf16.h>

typedef __bf16 bf16x8 __attribute__((ext_vector_type(8)));
typedef float f32x4 __attribute__((ext_vector_type(4)));

#define EPS 1e-5f
// 0.125 * log2(e): folded into Q via LN gamma/beta in qkv, so P = exp2(S)
#define QSCALE 0.18033688011112042f

__device__ __forceinline__ unsigned short f2bf(float f) {
  union { float f; unsigned int i; } c; c.f = f;
  unsigned int r = c.i + 0x7FFFu + ((c.i >> 16) & 1u);
  return (unsigned short)(r >> 16);
}

// -------- Transpose+convert: in fp32 [R,C] -> out bf16 [C,R], 64x64 tiles --
__global__ __launch_bounds__(256) void transpose_f32_bf16(
    const float* __restrict__ in, unsigned short* __restrict__ out,
    int R, int C)
{
  __shared__ __align__(16) unsigned short S[64 * 72];
  const int t = threadIdx.x;
  const int r = t >> 2, c4 = (t & 3) * 16;
  const int rt0 = blockIdx.y * 64, ct0 = blockIdx.x * 64;

  {
    long base = (long)(rt0 + r) * C + ct0 + c4;
    float4 a = *(const float4*)&in[base];
    float4 b = *(const float4*)&in[base + 4];
    float4 c = *(const float4*)&in[base + 8];
    float4 d = *(const float4*)&in[base + 12];
    unsigned short v[16] = {f2bf(a.x), f2bf(a.y), f2bf(a.z), f2bf(a.w),
                            f2bf(b.x), f2bf(b.y), f2bf(b.z), f2bf(b.w),
                            f2bf(c.x), f2bf(c.y), f2bf(c.z), f2bf(c.w),
                            f2bf(d.x), f2bf(d.y), f2bf(d.z), f2bf(d.w)};
    *(uint4*)&S[r * 72 + c4]     = *(uint4*)&v[0];
    *(uint4*)&S[r * 72 + c4 + 8] = *(uint4*)&v[8];
  }
  __syncthreads();

  unsigned short tmp[16];
#pragma unroll
  for (int j = 0; j < 16; j++) tmp[j] = S[(c4 + j) * 72 + r];
  *(uint4*)&out[(long)(ct0 + r) * R + rt0 + c4]     = *(uint4*)&tmp[0];
  *(uint4*)&out[(long)(ct0 + r) * R + rt0 + c4 + 8] = *(uint4*)&tmp[8];
}

// -------- Flat convert: fp32 -> bf16, 16 elems/thread ----------------------
__global__ __launch_bounds__(256) void convert_f32_bf16(
    const float* __restrict__ in, unsigned short* __restrict__ out)
{
  long i = ((long)blockIdx.x * 256 + threadIdx.x) * 16;
  float4 a = *(const float4*)&in[i];
  float4 b = *(const float4*)&in[i + 4];
  float4 c = *(const float4*)&in[i + 8];
  float4 d = *(const float4*)&in[i + 12];
  unsigned short v[16] = {f2bf(a.x), f2bf(a.y), f2bf(a.z), f2bf(a.w),
                          f2bf(b.x), f2bf(b.y), f2bf(b.z), f2bf(b.w),
                          f2bf(c.x), f2bf(c.y), f2bf(c.z), f2bf(c.w),
                          f2bf(d.x), f2bf(d.y), f2bf(d.z), f2bf(d.w)};
  *(uint4*)&out[i]     = *(uint4*)&v[0];
  *(uint4*)&out[i + 8] = *(uint4*)&v[8];
}

// ---------------- Kernel 1: Q/K GEMM 128x128, dbuf, 1 barrier (r12) -------
__global__ __launch_bounds__(256) void qkv_ln_kernel(
    const float* __restrict__ Xf,
    const unsigned short* __restrict__ Xbf, int use_xbf,
    const unsigned short* __restrict__ WT,
    const float* __restrict__ bias,
    const float* __restrict__ qg, const float* __restrict__ qb,
    const float* __restrict__ kg, const float* __restrict__ kb,
    unsigned short* __restrict__ Qws, unsigned short* __restrict__ Kws)
{
  __shared__ __align__(16) unsigned short As[2][128 * 32];
  __shared__ __align__(16) unsigned short Bs[2][128 * 32];

  const int tid = threadIdx.x;
  const int w = tid >> 6, lane = tid & 63, quad = lane >> 4, l15 = lane & 15;
  const int mh = w & 1, nh = w >> 1;
  const int n0 = blockIdx.x * 128, m0 = blockIdx.y * 128;

  f32x4 acc[4][4];
#pragma unroll
  for (int i = 0; i < 4; i++)
#pragma unroll
    for (int j = 0; j < 4; j++) acc[i][j] = (f32x4){0.f, 0.f, 0.f, 0.f};

  const int sr2 = tid >> 1, sh2 = (tid & 1) * 16;

  if (use_xbf) {
    long xo = (long)(m0 + sr2) * 1024 + sh2;
    *(uint4*)&As[0][sr2 * 32 + sh2]     = *(const uint4*)&Xbf[xo];
    *(uint4*)&As[0][sr2 * 32 + sh2 + 8] = *(const uint4*)&Xbf[xo + 8];
  } else {
    long xo = (long)(m0 + sr2) * 1024 + sh2;
    float4 a0 = *(const float4*)&Xf[xo];
    float4 a1 = *(const float4*)&Xf[xo + 4];
    float4 a2 = *(const float4*)&Xf[xo + 8];
    float4 a3 = *(const float4*)&Xf[xo + 12];
    unsigned short v[16] = {f2bf(a0.x), f2bf(a0.y), f2bf(a0.z), f2bf(a0.w),
                            f2bf(a1.x), f2bf(a1.y), f2bf(a1.z), f2bf(a1.w),
                            f2bf(a2.x), f2bf(a2.y), f2bf(a2.z), f2bf(a2.w),
                            f2bf(a3.x), f2bf(a3.y), f2bf(a3.z), f2bf(a3.w)};
    *(uint4*)&As[0][sr2 * 32 + sh2]     = *(uint4*)&v[0];
    *(uint4*)&As[0][sr2 * 32 + sh2 + 8] = *(uint4*)&v[8];
  }
  {
    long wo = (long)(n0 + sr2) * 1024 + sh2;
    *(uint4*)&Bs[0][sr2 * 32 + sh2]     = *(const uint4*)&WT[wo];
    *(uint4*)&Bs[0][sr2 * 32 + sh2 + 8] = *(const uint4*)&WT[wo + 8];
  }
  __syncthreads();

  int buf = 0;
  for (int kt = 0; kt < 1024; kt += 32) {
    const int nbuf = buf ^ 1;
    const bool pf = (kt + 32) < 1024;
    uint4 xv0, xv1, wv0, wv1;
    float4 a0, a1, a2, a3;
    if (pf) {
      if (use_xbf) {
        long xo = (long)(m0 + sr2) * 1024 + kt + 32 + sh2;
        xv0 = *(const uint4*)&Xbf[xo];
        xv1 = *(const uint4*)&Xbf[xo + 8];
      } else {
        long xo = (long)(m0 + sr2) * 1024 + kt + 32 + sh2;
        a0 = *(const float4*)&Xf[xo];
        a1 = *(const float4*)&Xf[xo + 4];
        a2 = *(const float4*)&Xf[xo + 8];
        a3 = *(const float4*)&Xf[xo + 12];
      }
      long wo = (long)(n0 + sr2) * 1024 + kt + 32 + sh2;
      wv0 = *(const uint4*)&WT[wo];
      wv1 = *(const uint4*)&WT[wo + 8];
    }

    bf16x8 af[4], bfr[4];
#pragma unroll
    for (int mq = 0; mq < 4; mq++)
      af[mq] = *(const bf16x8*)&As[buf][(mh * 64 + mq * 16 + l15) * 32 + quad * 8];
#pragma unroll
    for (int nq = 0; nq < 4; nq++)
      bfr[nq] = *(const bf16x8*)&Bs[buf][(nh * 64 + nq * 16 + l15) * 32 + quad * 8];
#pragma unroll
    for (int mq = 0; mq < 4; mq++)
#pragma unroll
      for (int nq = 0; nq < 4; nq++)
        acc[mq][nq] = __builtin_amdgcn_mfma_f32_16x16x32_bf16(af[mq], bfr[nq], acc[mq][nq], 0, 0, 0);

    if (pf) {
      if (use_xbf) {
        *(uint4*)&As[nbuf][sr2 * 32 + sh2]     = xv0;
        *(uint4*)&As[nbuf][sr2 * 32 + sh2 + 8] = xv1;
      } else {
        unsigned short v[16] = {f2bf(a0.x), f2bf(a0.y), f2bf(a0.z), f2bf(a0.w),
                                f2bf(a1.x), f2bf(a1.y), f2bf(a1.z), f2bf(a1.w),
                                f2bf(a2.x), f2bf(a2.y), f2bf(a2.z), f2bf(a2.w),
                                f2bf(a3.x), f2bf(a3.y), f2bf(a3.z), f2bf(a3.w)};
        *(uint4*)&As[nbuf][sr2 * 32 + sh2]     = *(uint4*)&v[0];
        *(uint4*)&As[nbuf][sr2 * 32 + sh2 + 8] = *(uint4*)&v[8];
      }
      *(uint4*)&Bs[nbuf][sr2 * 32 + sh2]     = wv0;
      *(uint4*)&Bs[nbuf][sr2 * 32 + sh2 + 8] = wv1;
    }
    __syncthreads();
    buf = nbuf;
  }

#pragma unroll
  for (int nq = 0; nq < 4; nq++) {
    float bv = bias[n0 + nh * 64 + nq * 16 + l15];
#pragma unroll
    for (int mq = 0; mq < 4; mq++)
#pragma unroll
      for (int rr = 0; rr < 4; rr++) acc[mq][nq][rr] += bv;
  }

  const int g = (n0 >> 6) + nh;   // 0..31: Q heads then K heads
  const bool isQ = g < 16;

  {
    float gv[4], bev[4];
#pragma unroll
    for (int nq = 0; nq < 4; nq++) {
      int d = nq * 16 + l15;
      gv[nq]  = isQ ? qg[d] : kg[d];
      bev[nq] = isQ ? qb[d] : kb[d];
      if (isQ) { gv[nq] *= QSCALE; bev[nq] *= QSCALE; }
    }
#pragma unroll
    for (int mq = 0; mq < 4; mq++)
#pragma unroll
      for (int rr = 0; rr < 4; rr++) {
        float s  = acc[mq][0][rr] + acc[mq][1][rr] + acc[mq][2][rr] + acc[mq][3][rr];
        float s2 = acc[mq][0][rr]*acc[mq][0][rr] + acc[mq][1][rr]*acc[mq][1][rr]
                 + acc[mq][2][rr]*acc[mq][2][rr] + acc[mq][3][rr]*acc[mq][3][rr];
#pragma unroll
        for (int off = 1; off < 16; off <<= 1) {
          s  += __shfl_xor(s,  off, 64);
          s2 += __shfl_xor(s2, off, 64);
        }
        float mu   = s * (1.0f / 64.0f);
        float var  = fmaxf(s2 * (1.0f / 64.0f) - mu * mu, 0.f);
        float rstd = rsqrtf(var + EPS);
#pragma unroll
        for (int nq = 0; nq < 4; nq++)
          acc[mq][nq][rr] = (acc[mq][nq][rr] - mu) * rstd * gv[nq] + bev[nq];
      }
  }

  unsigned short* dst = isQ ? Qws : Kws;
  const int head = isQ ? g : g - 16;

#pragma unroll
  for (int mq = 0; mq < 4; mq++)
#pragma unroll
    for (int rr = 0; rr < 4; rr++) {
      int m = m0 + mh * 64 + mq * 16 + quad * 4 + rr;
      int b = m >> 11, s = m & 2047;
      long base = ((long)((b * 16 + head) * 2048 + s)) * 64;
#pragma unroll
      for (int nq = 0; nq < 4; nq++)
        dst[base + nq * 16 + l15] = f2bf(acc[mq][nq][rr]);
    }
}

// ---------------- Kernel 1b: V^T GEMM, 128x64 tiles (2 blocks/CU) ---------
// Vt[bh][d][s] = Wv^T · X^T + bv. A=WvT rows (m=d+head*64), B=X rows (n=s).
__global__ __launch_bounds__(256) void vt_kernel(
    const float* __restrict__ Xf,
    const unsigned short* __restrict__ Xbf, int use_xbf,
    const unsigned short* __restrict__ WvT,
    const float* __restrict__ bias,           // b_attn; index 2048+m
    unsigned short* __restrict__ Vt)
{
  __shared__ __align__(16) unsigned short As[2][128 * 32];
  __shared__ __align__(16) unsigned short Bs[2][64 * 32];

  const int tid = threadIdx.x;
  const int w = tid >> 6, lane = tid & 63, quad = lane >> 4, l15 = lane & 15;
  const int mh = w & 1, nh = w >> 1;
  const int n0 = blockIdx.x * 64, m0 = blockIdx.y * 128, bz = blockIdx.z;
  const long xrow0 = (long)bz * 2048;

  f32x4 acc[4][2];
#pragma unroll
  for (int i = 0; i < 4; i++)
#pragma unroll
    for (int j = 0; j < 2; j++) acc[i][j] = (f32x4){0.f, 0.f, 0.f, 0.f};

  const int srA = tid >> 1, shA = (tid & 1) * 16;
  const int srB = tid >> 2, shB = (tid & 3) * 8;

  {
    long wo = (long)(m0 + srA) * 1024 + shA;
    *(uint4*)&As[0][srA * 32 + shA]     = *(const uint4*)&WvT[wo];
    *(uint4*)&As[0][srA * 32 + shA + 8] = *(const uint4*)&WvT[wo + 8];
  }
  if (use_xbf) {
    long xo = (xrow0 + n0 + srB) * 1024 + shB;
    *(uint4*)&Bs[0][srB * 32 + shB] = *(const uint4*)&Xbf[xo];
  } else {
    long xo = (xrow0 + n0 + srB) * 1024 + shB;
    float4 a0 = *(const float4*)&Xf[xo];
    float4 a1 = *(const float4*)&Xf[xo + 4];
    unsigned short v[8] = {f2bf(a0.x), f2bf(a0.y), f2bf(a0.z), f2bf(a0.w),
                           f2bf(a1.x), f2bf(a1.y), f2bf(a1.z), f2bf(a1.w)};
    *(uint4*)&Bs[0][srB * 32 + shB] = *(uint4*)v;
  }
  __syncthreads();

  int buf = 0;
  for (int kt = 0; kt < 1024; kt += 32) {
    const int nbuf = buf ^ 1;
    const bool pf = (kt + 32) < 1024;
    uint4 wv0, wv1, xv0;
    float4 a0, a1;
    if (pf) {
      long wo = (long)(m0 + srA) * 1024 + kt + 32 + shA;
      wv0 = *(const uint4*)&WvT[wo];
      wv1 = *(const uint4*)&WvT[wo + 8];
      long xo = (xrow0 + n0 + srB) * 1024 + kt + 32 + shB;
      if (use_xbf) {
        xv0 = *(const uint4*)&Xbf[xo];
      } else {
        a0 = *(const float4*)&Xf[xo];
        a1 = *(const float4*)&Xf[xo + 4];
      }
    }

    bf16x8 af[4], bfr[2];
#pragma unroll
    for (int mq = 0; mq < 4; mq++)
      af[mq] = *(const bf16x8*)&As[buf][(mh * 64 + mq * 16 + l15) * 32 + quad * 8];
#pragma unroll
    for (int nq = 0; nq < 2; nq++)
      bfr[nq] = *(const bf16x8*)&Bs[buf][(nh * 32 + nq * 16 + l15) * 32 + quad * 8];
#pragma unroll
    for (int mq = 0; mq < 4; mq++)
#pragma unroll
      for (int nq = 0; nq < 2; nq++)
        acc[mq][nq] = __builtin_amdgcn_mfma_f32_16x16x32_bf16(af[mq], bfr[nq], acc[mq][nq], 0, 0, 0);

    if (pf) {
      *(uint4*)&As[nbuf][srA * 32 + shA]     = wv0;
      *(uint4*)&As[nbuf][srA * 32 + shA + 8] = wv1;
      if (use_xbf) {
        *(uint4*)&Bs[nbuf][srB * 32 + shB] = xv0;
      } else {
        unsigned short v[8] = {f2bf(a0.x), f2bf(a0.y), f2bf(a0.z), f2bf(a0.w),
                               f2bf(a1.x), f2bf(a1.y), f2bf(a1.z), f2bf(a1.w)};
        *(uint4*)&Bs[nbuf][srB * 32 + shB] = *(uint4*)v;
      }
    }
    __syncthreads();
    buf = nbuf;
  }

  const long outb = (long)bz * 2097152;
#pragma unroll
  for (int mq = 0; mq < 4; mq++)
#pragma unroll
    for (int rr = 0; rr < 4; rr++) {
      int m = m0 + mh * 64 + mq * 16 + quad * 4 + rr;
      float bv = bias[2048 + m];
#pragma unroll
      for (int nq = 0; nq < 2; nq++) {
        int n = n0 + nh * 32 + nq * 16 + l15;
        Vt[outb + (long)m * 2048 + n] = f2bf(acc[mq][nq][rr] + bv);
      }
    }
}

// ---------------- Kernel 2: causal attention (round-12 + Q swizzle) -------
// 26.6KB LDS -> 6 blocks/CU: 1024-block grid fully resident; qt remap gives
// each CU constant 66 iteration-units. 2 barriers/iter, register prefetch.
__global__ __launch_bounds__(256, 6) void attn_kernel(
    unsigned short* __restrict__ Qws,        // in: Q (pre-scaled), out: O
    const unsigned short* __restrict__ Kws,
    const unsigned short* __restrict__ Vt)
{
  __shared__ __align__(16) unsigned short Ks[64 * 72];
  __shared__ __align__(16) unsigned short VTs[64 * 72];  // [d][s-kb]
  __shared__ __align__(16) unsigned short Ps[64 * 64];   // swizzled; Q staging

  const int tid = threadIdx.x;
  const int w = tid >> 6, lane = tid & 63, quad = lane >> 4, l15 = lane & 15;
  const int bh = blockIdx.y;
  const int qt = ((bh >> 3) & 1) ? blockIdx.x : (31 - blockIdx.x);
  const int qbase = qt * 64;
  const long bhoff = (long)bh * 2048 * 64;
  const long bhv   = (long)bh * 131072;      // 64*2048
  const int jmax = qt + 1;

  const int sr = tid >> 2, sc = (tid & 3) * 16;
  const int qsw = ((sr >> 2) & 3) << 4;      // Q staging swizzle (row group)

  // stage Q into Ps, XOR-swizzled (rows wave-private: wave w rows 16w..16w+15)
  *(uint4*)&Ps[sr * 64 + (sc ^ qsw)]       = *(const uint4*)&Qws[bhoff + (qbase + sr) * 64 + sc];
  *(uint4*)&Ps[sr * 64 + ((sc ^ qsw) + 8)] = *(const uint4*)&Qws[bhoff + (qbase + sr) * 64 + sc + 8];
  // stage K/VT tile j=0
  *(uint4*)&Ks[sr * 72 + sc]      = *(const uint4*)&Kws[bhoff + sr * 64 + sc];
  *(uint4*)&Ks[sr * 72 + sc + 8]  = *(const uint4*)&Kws[bhoff + sr * 64 + sc + 8];
  *(uint4*)&VTs[sr * 72 + sc]     = *(const uint4*)&Vt[bhv + sr * 2048 + sc];
  *(uint4*)&VTs[sr * 72 + sc + 8] = *(const uint4*)&Vt[bhv + sr * 2048 + sc + 8];
  __syncthreads();

  const int sw = ((l15 >> 2) & 3) << 4;
  const int pc0 = (quad * 8) ^ sw;
  const int pc1 = (32 + quad * 8) ^ sw;

  const bf16x8 qf0 = *(const bf16x8*)&Ps[(w * 16 + l15) * 64 + pc0];
  const bf16x8 qf1 = *(const bf16x8*)&Ps[(w * 16 + l15) * 64 + pc1];
  // no barrier: Ps rows wave-private for Q reads and P writes

  bf16x8 ones;
  {
    union { unsigned short u[8]; bf16x8 v; } c;
#pragma unroll
    for (int i = 0; i < 8; i++) c.u[i] = 0x3F80u;
    ones = c.v;
  }

  f32x4 o[4], osum;
#pragma unroll
  for (int i = 0; i < 4; i++) o[i] = (f32x4){0.f, 0.f, 0.f, 0.f};
  osum = (f32x4){0.f, 0.f, 0.f, 0.f};

  for (int j = 0; j < jmax; j++) {
    const int kb = j * 64;
    const bool pf = (j + 1) < jmax;
    uint4 pk0, pk1, pv0, pv1;
    if (pf) {
      const int kb1 = kb + 64;
      pk0 = *(const uint4*)&Kws[bhoff + (kb1 + sr) * 64 + sc];
      pk1 = *(const uint4*)&Kws[bhoff + (kb1 + sr) * 64 + sc + 8];
      pv0 = *(const uint4*)&Vt[bhv + sr * 2048 + kb1 + sc];
      pv1 = *(const uint4*)&Vt[bhv + sr * 2048 + kb1 + sc + 8];
    }

    // S = Q K^T
    f32x4 sacc[4];
#pragma unroll
    for (int i = 0; i < 4; i++) sacc[i] = (f32x4){0.f, 0.f, 0.f, 0.f};
#pragma unroll
    for (int nt = 0; nt < 4; nt++) {
      bf16x8 kf0 = *(const bf16x8*)&Ks[(nt * 16 + l15) * 72 + quad * 8];
      bf16x8 kf1 = *(const bf16x8*)&Ks[(nt * 16 + l15) * 72 + 32 + quad * 8];
      sacc[nt] = __builtin_amdgcn_mfma_f32_16x16x32_bf16(qf0, kf0, sacc[nt], 0, 0, 0);
      sacc[nt] = __builtin_amdgcn_mfma_f32_16x16x32_bf16(qf1, kf1, sacc[nt], 0, 0, 0);
    }

    // P = exp2(S); masked -> 0 (scale folded upstream; |S| <= 11.6)
    const bool domask = (j == qt);
#pragma unroll
    for (int nt = 0; nt < 4; nt++)
#pragma unroll
      for (int rr = 0; rr < 4; rr++) {
        float p = exp2f(sacc[nt][rr]);
        if (domask) {
          int kcol = kb + nt * 16 + l15;
          int qrow = qbase + w * 16 + quad * 4 + rr;
          if (kcol > qrow) p = 0.f;
        }
        sacc[nt][rr] = p;
      }

    // P: C-layout -> LDS (own rows), XOR chunk swizzle
#pragma unroll
    for (int rr = 0; rr < 4; rr++)
#pragma unroll
      for (int nt = 0; nt < 4; nt++)
        Ps[(w * 16 + quad * 4 + rr) * 64 + (((nt ^ quad) & 3) * 16 + l15)]
            = f2bf(sacc[nt][rr]);

    bf16x8 pfr0 = *(const bf16x8*)&Ps[(w * 16 + l15) * 64 + pc0];
    bf16x8 pfr1 = *(const bf16x8*)&Ps[(w * 16 + l15) * 64 + pc1];

    osum = __builtin_amdgcn_mfma_f32_16x16x32_bf16(pfr0, ones, osum, 0, 0, 0);
    osum = __builtin_amdgcn_mfma_f32_16x16x32_bf16(pfr1, ones, osum, 0, 0, 0);
#pragma unroll
    for (int dt = 0; dt < 4; dt++) {
      bf16x8 vf0 = *(const bf16x8*)&VTs[(dt * 16 + l15) * 72 + quad * 8];
      bf16x8 vf1 = *(const bf16x8*)&VTs[(dt * 16 + l15) * 72 + 32 + quad * 8];
      o[dt] = __builtin_amdgcn_mfma_f32_16x16x32_bf16(pfr0, vf0, o[dt], 0, 0, 0);
      o[dt] = __builtin_amdgcn_mfma_f32_16x16x32_bf16(pfr1, vf1, o[dt], 0, 0, 0);
    }

    if (pf) {
      __syncthreads();   // all waves done reading Ks/VTs
      *(uint4*)&Ks[sr * 72 + sc]      = pk0;
      *(uint4*)&Ks[sr * 72 + sc + 8]  = pk1;
      *(uint4*)&VTs[sr * 72 + sc]     = pv0;
      *(uint4*)&VTs[sr * 72 + sc + 8] = pv1;
      __syncthreads();   // staging visible
    }
  }

  // write O in-place over this block's Q rows
#pragma unroll
  for (int rr = 0; rr < 4; rr++) {
    float inv = 1.0f / osum[rr];
    int row = qbase + w * 16 + quad * 4 + rr;
    long base = bhoff + (long)row * 64;
#pragma unroll
    for (int dt = 0; dt < 4; dt++)
      Qws[base + dt * 16 + l15] = f2bf(o[dt][rr] * inv);
  }
}

// ---------------- Kernel 3: output projection, 128x64 tiles (2 blocks/CU) -
__global__ __launch_bounds__(256) void proj_kernel(
    const unsigned short* __restrict__ AQ,
    const unsigned short* __restrict__ WT,
    const float* __restrict__ bias,
    float* __restrict__ Out)
{
  __shared__ __align__(16) unsigned short As[2][128 * 32];
  __shared__ __align__(16) unsigned short Bs[2][64 * 32];

  const int tid = threadIdx.x;
  const int w = tid >> 6, lane = tid & 63, quad = lane >> 4, l15 = lane & 15;
  const int mh = w & 1, nh = w >> 1;
  const int n0 = blockIdx.x * 64, m0 = blockIdx.y * 128;

  f32x4 acc[4][2];
#pragma unroll
  for (int i = 0; i < 4; i++)
#pragma unroll
    for (int j = 0; j < 2; j++) acc[i][j] = (f32x4){0.f, 0.f, 0.f, 0.f};

  const int srA = tid >> 1, shA = (tid & 1) * 16;
  const int srB = tid >> 2, shB = (tid & 3) * 8;
  const int m = m0 + srA, b = m >> 11, s = m & 2047;

  {
    const int h = shA >> 6, d = shA & 63;
    long ao = ((long)((b * 16 + h) * 2048 + s)) * 64 + d;
    *(uint4*)&As[0][srA * 32 + shA]     = *(const uint4*)&AQ[ao];
    *(uint4*)&As[0][srA * 32 + shA + 8] = *(const uint4*)&AQ[ao + 8];
    long wo = (long)(n0 + srB) * 1024 + shB;
    *(uint4*)&Bs[0][srB * 32 + shB] = *(const uint4*)&WT[wo];
  }
  __syncthreads();

  int buf = 0;
  for (int kt = 0; kt < 1024; kt += 32) {
    const int nbuf = buf ^ 1;
    const bool pf = (kt + 32) < 1024;
    uint4 av0, av1, wv0;
    if (pf) {
      const int k = kt + 32 + shA, h = k >> 6, d = k & 63;
      long ao = ((long)((b * 16 + h) * 2048 + s)) * 64 + d;
      av0 = *(const uint4*)&AQ[ao];
      av1 = *(const uint4*)&AQ[ao + 8];
      long wo = (long)(n0 + srB) * 1024 + kt + 32 + shB;
      wv0 = *(const uint4*)&WT[wo];
    }

    bf16x8 af[4], bfr[2];
#pragma unroll
    for (int mq = 0; mq < 4; mq++)
      af[mq] = *(const bf16x8*)&As[buf][(mh * 64 + mq * 16 + l15) * 32 + quad * 8];
#pragma unroll
    for (int nq = 0; nq < 2; nq++)
      bfr[nq] = *(const bf16x8*)&Bs[buf][(nh * 32 + nq * 16 + l15) * 32 + quad * 8];
#pragma unroll
    for (int mq = 0; mq < 4; mq++)
#pragma unroll
      for (int nq = 0; nq < 2; nq++)
        acc[mq][nq] = __builtin_amdgcn_mfma_f32_16x16x32_bf16(af[mq], bfr[nq], acc[mq][nq], 0, 0, 0);

    if (pf) {
      *(uint4*)&As[nbuf][srA * 32 + shA]     = av0;
      *(uint4*)&As[nbuf][srA * 32 + shA + 8] = av1;
      *(uint4*)&Bs[nbuf][srB * 32 + shB]     = wv0;
    }
    __syncthreads();
    buf = nbuf;
  }

#pragma unroll
  for (int nq = 0; nq < 2; nq++) {
    int n = n0 + nh * 32 + nq * 16 + l15;
    float bv = bias[n];
#pragma unroll
    for (int mq = 0; mq < 4; mq++)
#pragma unroll
      for (int rr = 0; rr < 4; rr++) {
        int mm = m0 + mh * 64 + mq * 16 + quad * 4 + rr;
        Out[(long)mm * 1024 + n] = acc[mq][nq][rr] + bv;
      }
  }
}

extern "C" void kernel_launch(void* const* d_in, const int* in_sizes, int n_in,
                              void* d_out, int out_size, void* d_ws, size_t ws_size,
                              hipStream_t stream) {
  const float* X  = (const float*)d_in[0];
  const float* Wa = (const float*)d_in[1];
  const float* ba = (const float*)d_in[2];
  const float* Wp = (const float*)d_in[3];
  const float* bp = (const float*)d_in[4];
  const float* qg = (const float*)d_in[5];
  const float* qb = (const float*)d_in[6];
  const float* kg = (const float*)d_in[7];
  const float* kb = (const float*)d_in[8];

  const long per = 2L * 16 * 2048 * 64;     // 4,194,304 shorts
  unsigned short* ws  = (unsigned short*)d_ws;
  unsigned short* Qws = ws;
  unsigned short* Kws = Qws + per;
  unsigned short* Vt  = Kws + per;          // [bh][64 d][2048 s]

  const bool big = ws_size >= (size_t)(5L * per * 2);
  unsigned short *Xbf, *WaT, *WpT;
  if (big) {
    Xbf = Vt + per;
    WaT = Xbf + per;
    WpT = WaT + 3072L * 1024;
  } else {
    Xbf = Qws;  // unused
    WaT = Vt + per;
    WpT = WaT + 3072L * 1024;
  }
  unsigned short* WvT = WaT + 2048L * 1024;   // V rows of WaT

  transpose_f32_bf16<<<dim3(48, 16), 256, 0, stream>>>(Wa, WaT, 1024, 3072);
  transpose_f32_bf16<<<dim3(16, 16), 256, 0, stream>>>(Wp, WpT, 1024, 1024);
  if (big) convert_f32_bf16<<<1024, 256, 0, stream>>>(X, Xbf);
  qkv_ln_kernel<<<dim3(16, 32), 256, 0, stream>>>(X, Xbf, big ? 1 : 0, WaT, ba,
                                                  qg, qb, kg, kb, Qws, Kws);
  vt_kernel<<<dim3(32, 8, 2), 256, 0, stream>>>(X, Xbf, big ? 1 : 0, WvT, ba, Vt);
  attn_kernel<<<dim3(32, 32), 256, 0, stream>>>(Qws, Kws, Vt);
  proj_kernel<<<dim3(16, 32), 256, 0, stream>>>(Qws, WpT, bp, (float*)d_out);
}

// Round 15
// 208.777 us; speedup vs baseline: 1.1294x; 1.0625x over previous
//
#include <hip/hip_runtime.h>
#include <hip/hip_bf16.h>

typedef __bf16 bf16x8 __attribute__((ext_vector_type(8)));
typedef float f32x4 __attribute__((ext_vector_type(4)));

#define EPS 1e-5f
// 0.125 * log2(e): folded into Q via LN gamma/beta in qkv, so P = exp2(S)
#define QSCALE 0.18033688011112042f

__device__ __forceinline__ unsigned short f2bf(float f) {
  union { float f; unsigned int i; } c; c.f = f;
  unsigned int r = c.i + 0x7FFFu + ((c.i >> 16) & 1u);
  return (unsigned short)(r >> 16);
}

// ---------------- Prep: both weight transposes + optional X convert -------
__device__ __forceinline__ void transpose_tile(
    const float* __restrict__ in, unsigned short* __restrict__ out,
    int R, int C, int ct0, int rt0, unsigned short* S /*64*72*/)
{
  const int t = threadIdx.x;
  const int r = t >> 2, c4 = (t & 3) * 16;
  {
    long base = (long)(rt0 + r) * C + ct0 + c4;
    float4 a = *(const float4*)&in[base];
    float4 b = *(const float4*)&in[base + 4];
    float4 c = *(const float4*)&in[base + 8];
    float4 d = *(const float4*)&in[base + 12];
    unsigned short v[16] = {f2bf(a.x), f2bf(a.y), f2bf(a.z), f2bf(a.w),
                            f2bf(b.x), f2bf(b.y), f2bf(b.z), f2bf(b.w),
                            f2bf(c.x), f2bf(c.y), f2bf(c.z), f2bf(c.w),
                            f2bf(d.x), f2bf(d.y), f2bf(d.z), f2bf(d.w)};
    *(uint4*)&S[r * 72 + c4]     = *(uint4*)&v[0];
    *(uint4*)&S[r * 72 + c4 + 8] = *(uint4*)&v[8];
  }
  __syncthreads();
  unsigned short tmp[16];
#pragma unroll
  for (int j = 0; j < 16; j++) tmp[j] = S[(c4 + j) * 72 + r];
  *(uint4*)&out[(long)(ct0 + r) * R + rt0 + c4]     = *(uint4*)&tmp[0];
  *(uint4*)&out[(long)(ct0 + r) * R + rt0 + c4 + 8] = *(uint4*)&tmp[8];
}

__global__ __launch_bounds__(256) void prep_kernel(
    const float* __restrict__ Wa, const float* __restrict__ Wp,
    const float* __restrict__ X,
    unsigned short* __restrict__ WaT, unsigned short* __restrict__ WpT,
    unsigned short* __restrict__ Xbf)
{
  __shared__ __align__(16) unsigned short S[64 * 72];
  const int id = blockIdx.x;
  if (id < 768) {                    // Wa [1024,3072] -> WaT [3072,1024]
    transpose_tile(Wa, WaT, 1024, 3072, (id % 48) * 64, (id / 48) * 64, S);
  } else if (id < 1024) {            // Wp [1024,1024] -> WpT [1024,1024]
    const int i2 = id - 768;
    transpose_tile(Wp, WpT, 1024, 1024, (i2 % 16) * 64, (i2 / 16) * 64, S);
  } else {                           // X fp32 -> bf16 (big-ws only)
    long i = ((long)(id - 1024) * 256 + threadIdx.x) * 16;
    float4 a = *(const float4*)&X[i];
    float4 b = *(const float4*)&X[i + 4];
    float4 c = *(const float4*)&X[i + 8];
    float4 d = *(const float4*)&X[i + 12];
    unsigned short v[16] = {f2bf(a.x), f2bf(a.y), f2bf(a.z), f2bf(a.w),
                            f2bf(b.x), f2bf(b.y), f2bf(b.z), f2bf(b.w),
                            f2bf(c.x), f2bf(c.y), f2bf(c.z), f2bf(c.w),
                            f2bf(d.x), f2bf(d.y), f2bf(d.z), f2bf(d.w)};
    *(uint4*)&Xbf[i]     = *(uint4*)&v[0];
    *(uint4*)&Xbf[i + 8] = *(uint4*)&v[8];
  }
}

// ---------------- Kernel 1: Q/K GEMM 128x128, dbuf (r14 proven) -----------
__global__ __launch_bounds__(256) void qkv_ln_kernel(
    const float* __restrict__ Xf,
    const unsigned short* __restrict__ Xbf, int use_xbf,
    const unsigned short* __restrict__ WT,
    const float* __restrict__ bias,
    const float* __restrict__ qg, const float* __restrict__ qb,
    const float* __restrict__ kg, const float* __restrict__ kb,
    unsigned short* __restrict__ Qws, unsigned short* __restrict__ Kws)
{
  __shared__ __align__(16) unsigned short As[2][128 * 32];
  __shared__ __align__(16) unsigned short Bs[2][128 * 32];

  const int tid = threadIdx.x;
  const int w = tid >> 6, lane = tid & 63, quad = lane >> 4, l15 = lane & 15;
  const int mh = w & 1, nh = w >> 1;
  const int n0 = blockIdx.x * 128, m0 = blockIdx.y * 128;

  f32x4 acc[4][4];
#pragma unroll
  for (int i = 0; i < 4; i++)
#pragma unroll
    for (int j = 0; j < 4; j++) acc[i][j] = (f32x4){0.f, 0.f, 0.f, 0.f};

  const int sr2 = tid >> 1, sh2 = (tid & 1) * 16;

  if (use_xbf) {
    long xo = (long)(m0 + sr2) * 1024 + sh2;
    *(uint4*)&As[0][sr2 * 32 + sh2]     = *(const uint4*)&Xbf[xo];
    *(uint4*)&As[0][sr2 * 32 + sh2 + 8] = *(const uint4*)&Xbf[xo + 8];
  } else {
    long xo = (long)(m0 + sr2) * 1024 + sh2;
    float4 a0 = *(const float4*)&Xf[xo];
    float4 a1 = *(const float4*)&Xf[xo + 4];
    float4 a2 = *(const float4*)&Xf[xo + 8];
    float4 a3 = *(const float4*)&Xf[xo + 12];
    unsigned short v[16] = {f2bf(a0.x), f2bf(a0.y), f2bf(a0.z), f2bf(a0.w),
                            f2bf(a1.x), f2bf(a1.y), f2bf(a1.z), f2bf(a1.w),
                            f2bf(a2.x), f2bf(a2.y), f2bf(a2.z), f2bf(a2.w),
                            f2bf(a3.x), f2bf(a3.y), f2bf(a3.z), f2bf(a3.w)};
    *(uint4*)&As[0][sr2 * 32 + sh2]     = *(uint4*)&v[0];
    *(uint4*)&As[0][sr2 * 32 + sh2 + 8] = *(uint4*)&v[8];
  }
  {
    long wo = (long)(n0 + sr2) * 1024 + sh2;
    *(uint4*)&Bs[0][sr2 * 32 + sh2]     = *(const uint4*)&WT[wo];
    *(uint4*)&Bs[0][sr2 * 32 + sh2 + 8] = *(const uint4*)&WT[wo + 8];
  }
  __syncthreads();

  int buf = 0;
  for (int kt = 0; kt < 1024; kt += 32) {
    const int nbuf = buf ^ 1;
    const bool pf = (kt + 32) < 1024;
    uint4 xv0, xv1, wv0, wv1;
    float4 a0, a1, a2, a3;
    if (pf) {
      if (use_xbf) {
        long xo = (long)(m0 + sr2) * 1024 + kt + 32 + sh2;
        xv0 = *(const uint4*)&Xbf[xo];
        xv1 = *(const uint4*)&Xbf[xo + 8];
      } else {
        long xo = (long)(m0 + sr2) * 1024 + kt + 32 + sh2;
        a0 = *(const float4*)&Xf[xo];
        a1 = *(const float4*)&Xf[xo + 4];
        a2 = *(const float4*)&Xf[xo + 8];
        a3 = *(const float4*)&Xf[xo + 12];
      }
      long wo = (long)(n0 + sr2) * 1024 + kt + 32 + sh2;
      wv0 = *(const uint4*)&WT[wo];
      wv1 = *(const uint4*)&WT[wo + 8];
    }

    bf16x8 af[4], bfr[4];
#pragma unroll
    for (int mq = 0; mq < 4; mq++)
      af[mq] = *(const bf16x8*)&As[buf][(mh * 64 + mq * 16 + l15) * 32 + quad * 8];
#pragma unroll
    for (int nq = 0; nq < 4; nq++)
      bfr[nq] = *(const bf16x8*)&Bs[buf][(nh * 64 + nq * 16 + l15) * 32 + quad * 8];
#pragma unroll
    for (int mq = 0; mq < 4; mq++)
#pragma unroll
      for (int nq = 0; nq < 4; nq++)
        acc[mq][nq] = __builtin_amdgcn_mfma_f32_16x16x32_bf16(af[mq], bfr[nq], acc[mq][nq], 0, 0, 0);

    if (pf) {
      if (use_xbf) {
        *(uint4*)&As[nbuf][sr2 * 32 + sh2]     = xv0;
        *(uint4*)&As[nbuf][sr2 * 32 + sh2 + 8] = xv1;
      } else {
        unsigned short v[16] = {f2bf(a0.x), f2bf(a0.y), f2bf(a0.z), f2bf(a0.w),
                                f2bf(a1.x), f2bf(a1.y), f2bf(a1.z), f2bf(a1.w),
                                f2bf(a2.x), f2bf(a2.y), f2bf(a2.z), f2bf(a2.w),
                                f2bf(a3.x), f2bf(a3.y), f2bf(a3.z), f2bf(a3.w)};
        *(uint4*)&As[nbuf][sr2 * 32 + sh2]     = *(uint4*)&v[0];
        *(uint4*)&As[nbuf][sr2 * 32 + sh2 + 8] = *(uint4*)&v[8];
      }
      *(uint4*)&Bs[nbuf][sr2 * 32 + sh2]     = wv0;
      *(uint4*)&Bs[nbuf][sr2 * 32 + sh2 + 8] = wv1;
    }
    __syncthreads();
    buf = nbuf;
  }

#pragma unroll
  for (int nq = 0; nq < 4; nq++) {
    float bv = bias[n0 + nh * 64 + nq * 16 + l15];
#pragma unroll
    for (int mq = 0; mq < 4; mq++)
#pragma unroll
      for (int rr = 0; rr < 4; rr++) acc[mq][nq][rr] += bv;
  }

  const int g = (n0 >> 6) + nh;   // 0..31: Q heads then K heads
  const bool isQ = g < 16;

  {
    float gv[4], bev[4];
#pragma unroll
    for (int nq = 0; nq < 4; nq++) {
      int d = nq * 16 + l15;
      gv[nq]  = isQ ? qg[d] : kg[d];
      bev[nq] = isQ ? qb[d] : kb[d];
      if (isQ) { gv[nq] *= QSCALE; bev[nq] *= QSCALE; }
    }
#pragma unroll
    for (int mq = 0; mq < 4; mq++)
#pragma unroll
      for (int rr = 0; rr < 4; rr++) {
        float s  = acc[mq][0][rr] + acc[mq][1][rr] + acc[mq][2][rr] + acc[mq][3][rr];
        float s2 = acc[mq][0][rr]*acc[mq][0][rr] + acc[mq][1][rr]*acc[mq][1][rr]
                 + acc[mq][2][rr]*acc[mq][2][rr] + acc[mq][3][rr]*acc[mq][3][rr];
#pragma unroll
        for (int off = 1; off < 16; off <<= 1) {
          s  += __shfl_xor(s,  off, 64);
          s2 += __shfl_xor(s2, off, 64);
        }
        float mu   = s * (1.0f / 64.0f);
        float var  = fmaxf(s2 * (1.0f / 64.0f) - mu * mu, 0.f);
        float rstd = rsqrtf(var + EPS);
#pragma unroll
        for (int nq = 0; nq < 4; nq++)
          acc[mq][nq][rr] = (acc[mq][nq][rr] - mu) * rstd * gv[nq] + bev[nq];
      }
  }

  unsigned short* dst = isQ ? Qws : Kws;
  const int head = isQ ? g : g - 16;

#pragma unroll
  for (int mq = 0; mq < 4; mq++)
#pragma unroll
    for (int rr = 0; rr < 4; rr++) {
      int m = m0 + mh * 64 + mq * 16 + quad * 4 + rr;
      int b = m >> 11, s = m & 2047;
      long base = ((long)((b * 16 + head) * 2048 + s)) * 64;
#pragma unroll
      for (int nq = 0; nq < 4; nq++)
        dst[base + nq * 16 + l15] = f2bf(acc[mq][nq][rr]);
    }
}

// ---------------- Kernel 1b: V^T GEMM, 128x64 tiles (r14 proven) ----------
__global__ __launch_bounds__(256) void vt_kernel(
    const float* __restrict__ Xf,
    const unsigned short* __restrict__ Xbf, int use_xbf,
    const unsigned short* __restrict__ WvT,
    const float* __restrict__ bias,           // b_attn; index 2048+m
    unsigned short* __restrict__ Vt)
{
  __shared__ __align__(16) unsigned short As[2][128 * 32];
  __shared__ __align__(16) unsigned short Bs[2][64 * 32];

  const int tid = threadIdx.x;
  const int w = tid >> 6, lane = tid & 63, quad = lane >> 4, l15 = lane & 15;
  const int mh = w & 1, nh = w >> 1;
  const int n0 = blockIdx.x * 64, m0 = blockIdx.y * 128, bz = blockIdx.z;
  const long xrow0 = (long)bz * 2048;

  f32x4 acc[4][2];
#pragma unroll
  for (int i = 0; i < 4; i++)
#pragma unroll
    for (int j = 0; j < 2; j++) acc[i][j] = (f32x4){0.f, 0.f, 0.f, 0.f};

  const int srA = tid >> 1, shA = (tid & 1) * 16;
  const int srB = tid >> 2, shB = (tid & 3) * 8;

  {
    long wo = (long)(m0 + srA) * 1024 + shA;
    *(uint4*)&As[0][srA * 32 + shA]     = *(const uint4*)&WvT[wo];
    *(uint4*)&As[0][srA * 32 + shA + 8] = *(const uint4*)&WvT[wo + 8];
  }
  if (use_xbf) {
    long xo = (xrow0 + n0 + srB) * 1024 + shB;
    *(uint4*)&Bs[0][srB * 32 + shB] = *(const uint4*)&Xbf[xo];
  } else {
    long xo = (xrow0 + n0 + srB) * 1024 + shB;
    float4 a0 = *(const float4*)&Xf[xo];
    float4 a1 = *(const float4*)&Xf[xo + 4];
    unsigned short v[8] = {f2bf(a0.x), f2bf(a0.y), f2bf(a0.z), f2bf(a0.w),
                           f2bf(a1.x), f2bf(a1.y), f2bf(a1.z), f2bf(a1.w)};
    *(uint4*)&Bs[0][srB * 32 + shB] = *(uint4*)v;
  }
  __syncthreads();

  int buf = 0;
  for (int kt = 0; kt < 1024; kt += 32) {
    const int nbuf = buf ^ 1;
    const bool pf = (kt + 32) < 1024;
    uint4 wv0, wv1, xv0;
    float4 a0, a1;
    if (pf) {
      long wo = (long)(m0 + srA) * 1024 + kt + 32 + shA;
      wv0 = *(const uint4*)&WvT[wo];
      wv1 = *(const uint4*)&WvT[wo + 8];
      long xo = (xrow0 + n0 + srB) * 1024 + kt + 32 + shB;
      if (use_xbf) {
        xv0 = *(const uint4*)&Xbf[xo];
      } else {
        a0 = *(const float4*)&Xf[xo];
        a1 = *(const float4*)&Xf[xo + 4];
      }
    }

    bf16x8 af[4], bfr[2];
#pragma unroll
    for (int mq = 0; mq < 4; mq++)
      af[mq] = *(const bf16x8*)&As[buf][(mh * 64 + mq * 16 + l15) * 32 + quad * 8];
#pragma unroll
    for (int nq = 0; nq < 2; nq++)
      bfr[nq] = *(const bf16x8*)&Bs[buf][(nh * 32 + nq * 16 + l15) * 32 + quad * 8];
#pragma unroll
    for (int mq = 0; mq < 4; mq++)
#pragma unroll
      for (int nq = 0; nq < 2; nq++)
        acc[mq][nq] = __builtin_amdgcn_mfma_f32_16x16x32_bf16(af[mq], bfr[nq], acc[mq][nq], 0, 0, 0);

    if (pf) {
      *(uint4*)&As[nbuf][srA * 32 + shA]     = wv0;
      *(uint4*)&As[nbuf][srA * 32 + shA + 8] = wv1;
      if (use_xbf) {
        *(uint4*)&Bs[nbuf][srB * 32 + shB] = xv0;
      } else {
        unsigned short v[8] = {f2bf(a0.x), f2bf(a0.y), f2bf(a0.z), f2bf(a0.w),
                               f2bf(a1.x), f2bf(a1.y), f2bf(a1.z), f2bf(a1.w)};
        *(uint4*)&Bs[nbuf][srB * 32 + shB] = *(uint4*)v;
      }
    }
    __syncthreads();
    buf = nbuf;
  }

  const long outb = (long)bz * 2097152;
#pragma unroll
  for (int mq = 0; mq < 4; mq++)
#pragma unroll
    for (int rr = 0; rr < 4; rr++) {
      int m = m0 + mh * 64 + mq * 16 + quad * 4 + rr;
      float bv = bias[2048 + m];
#pragma unroll
      for (int nq = 0; nq < 2; nq++) {
        int n = n0 + nh * 32 + nq * 16 + l15;
        Vt[outb + (long)m * 2048 + n] = f2bf(acc[mq][nq][rr] + bv);
      }
    }
}

// ---------------- Kernel 2: causal attention, UNIFORM 33-unit blocks ------
// Each block processes q-tile pair {x, 31-x} sequentially -> every block
// does exactly 33 j-iterations. 512 identical-length blocks => no CU idle
// (fixes r12-r14's 52% slot utilization under full residency).
__global__ __launch_bounds__(256) void attn_kernel(
    unsigned short* __restrict__ Qws,        // in: Q (pre-scaled), out: O
    const unsigned short* __restrict__ Kws,
    const unsigned short* __restrict__ Vt)
{
  __shared__ __align__(16) unsigned short Ks[64 * 72];
  __shared__ __align__(16) unsigned short VTs[64 * 72];  // [d][s-kb]
  __shared__ __align__(16) unsigned short Ps[64 * 64];   // swizzled; Q staging

  const int tid = threadIdx.x;
  const int w = tid >> 6, lane = tid & 63, quad = lane >> 4, l15 = lane & 15;
  const int bh = blockIdx.y;
  const long bhoff = (long)bh * 2048 * 64;
  const long bhv   = (long)bh * 131072;      // 64*2048

  const int sr = tid >> 2, sc = (tid & 3) * 16;
  const int qsw = ((sr >> 2) & 3) << 4;      // Q staging swizzle (row group)
  const int sw = ((l15 >> 2) & 3) << 4;
  const int pc0 = (quad * 8) ^ sw;
  const int pc1 = (32 + quad * 8) ^ sw;

  bf16x8 ones;
  {
    union { unsigned short u[8]; bf16x8 v; } c;
#pragma unroll
    for (int i = 0; i < 8; i++) c.u[i] = 0x3F80u;
    ones = c.v;
  }

#pragma unroll
  for (int ph = 0; ph < 2; ph++) {
    const int qt = ph ? (31 - blockIdx.x) : blockIdx.x;
    const int qbase = qt * 64;
    const int jmax = qt + 1;

    if (ph) __syncthreads();   // all waves done with previous phase's tiles

    // stage Q into Ps, XOR-swizzled (rows wave-private)
    *(uint4*)&Ps[sr * 64 + (sc ^ qsw)]       = *(const uint4*)&Qws[bhoff + (qbase + sr) * 64 + sc];
    *(uint4*)&Ps[sr * 64 + ((sc ^ qsw) + 8)] = *(const uint4*)&Qws[bhoff + (qbase + sr) * 64 + sc + 8];
    // stage K/VT tile j=0
    *(uint4*)&Ks[sr * 72 + sc]      = *(const uint4*)&Kws[bhoff + sr * 64 + sc];
    *(uint4*)&Ks[sr * 72 + sc + 8]  = *(const uint4*)&Kws[bhoff + sr * 64 + sc + 8];
    *(uint4*)&VTs[sr * 72 + sc]     = *(const uint4*)&Vt[bhv + sr * 2048 + sc];
    *(uint4*)&VTs[sr * 72 + sc + 8] = *(const uint4*)&Vt[bhv + sr * 2048 + sc + 8];
    __syncthreads();

    const bf16x8 qf0 = *(const bf16x8*)&Ps[(w * 16 + l15) * 64 + pc0];
    const bf16x8 qf1 = *(const bf16x8*)&Ps[(w * 16 + l15) * 64 + pc1];
    // no barrier: Ps rows wave-private for Q reads and P writes

    f32x4 o[4], osum;
#pragma unroll
    for (int i = 0; i < 4; i++) o[i] = (f32x4){0.f, 0.f, 0.f, 0.f};
    osum = (f32x4){0.f, 0.f, 0.f, 0.f};

    for (int j = 0; j < jmax; j++) {
      const int kb = j * 64;
      const bool pf = (j + 1) < jmax;
      uint4 pk0, pk1, pv0, pv1;
      if (pf) {
        const int kb1 = kb + 64;
        pk0 = *(const uint4*)&Kws[bhoff + (kb1 + sr) * 64 + sc];
        pk1 = *(const uint4*)&Kws[bhoff + (kb1 + sr) * 64 + sc + 8];
        pv0 = *(const uint4*)&Vt[bhv + sr * 2048 + kb1 + sc];
        pv1 = *(const uint4*)&Vt[bhv + sr * 2048 + kb1 + sc + 8];
      }

      // S = Q K^T
      f32x4 sacc[4];
#pragma unroll
      for (int i = 0; i < 4; i++) sacc[i] = (f32x4){0.f, 0.f, 0.f, 0.f};
#pragma unroll
      for (int nt = 0; nt < 4; nt++) {
        bf16x8 kf0 = *(const bf16x8*)&Ks[(nt * 16 + l15) * 72 + quad * 8];
        bf16x8 kf1 = *(const bf16x8*)&Ks[(nt * 16 + l15) * 72 + 32 + quad * 8];
        sacc[nt] = __builtin_amdgcn_mfma_f32_16x16x32_bf16(qf0, kf0, sacc[nt], 0, 0, 0);
        sacc[nt] = __builtin_amdgcn_mfma_f32_16x16x32_bf16(qf1, kf1, sacc[nt], 0, 0, 0);
      }

      // P = exp2(S); masked -> 0 (scale folded upstream; |S| <= 11.6)
      const bool domask = (j == qt);
#pragma unroll
      for (int nt = 0; nt < 4; nt++)
#pragma unroll
        for (int rr = 0; rr < 4; rr++) {
          float p = exp2f(sacc[nt][rr]);
          if (domask) {
            int kcol = kb + nt * 16 + l15;
            int qrow = qbase + w * 16 + quad * 4 + rr;
            if (kcol > qrow) p = 0.f;
          }
          sacc[nt][rr] = p;
        }

      // P: C-layout -> LDS (own rows), XOR chunk swizzle
#pragma unroll
      for (int rr = 0; rr < 4; rr++)
#pragma unroll
        for (int nt = 0; nt < 4; nt++)
          Ps[(w * 16 + quad * 4 + rr) * 64 + (((nt ^ quad) & 3) * 16 + l15)]
              = f2bf(sacc[nt][rr]);

      bf16x8 pfr0 = *(const bf16x8*)&Ps[(w * 16 + l15) * 64 + pc0];
      bf16x8 pfr1 = *(const bf16x8*)&Ps[(w * 16 + l15) * 64 + pc1];

      osum = __builtin_amdgcn_mfma_f32_16x16x32_bf16(pfr0, ones, osum, 0, 0, 0);
      osum = __builtin_amdgcn_mfma_f32_16x16x32_bf16(pfr1, ones, osum, 0, 0, 0);
#pragma unroll
      for (int dt = 0; dt < 4; dt++) {
        bf16x8 vf0 = *(const bf16x8*)&VTs[(dt * 16 + l15) * 72 + quad * 8];
        bf16x8 vf1 = *(const bf16x8*)&VTs[(dt * 16 + l15) * 72 + 32 + quad * 8];
        o[dt] = __builtin_amdgcn_mfma_f32_16x16x32_bf16(pfr0, vf0, o[dt], 0, 0, 0);
        o[dt] = __builtin_amdgcn_mfma_f32_16x16x32_bf16(pfr1, vf1, o[dt], 0, 0, 0);
      }

      if (pf) {
        __syncthreads();   // all waves done reading Ks/VTs
        *(uint4*)&Ks[sr * 72 + sc]      = pk0;
        *(uint4*)&Ks[sr * 72 + sc + 8]  = pk1;
        *(uint4*)&VTs[sr * 72 + sc]     = pv0;
        *(uint4*)&VTs[sr * 72 + sc + 8] = pv1;
        __syncthreads();   // staging visible
      }
    }

    // write O in-place over this phase's Q rows
#pragma unroll
    for (int rr = 0; rr < 4; rr++) {
      float inv = 1.0f / osum[rr];
      int row = qbase + w * 16 + quad * 4 + rr;
      long base = bhoff + (long)row * 64;
#pragma unroll
      for (int dt = 0; dt < 4; dt++)
        Qws[base + dt * 16 + l15] = f2bf(o[dt][rr] * inv);
    }
  }
}

// ---------------- Kernel 3: output projection, 128x64 tiles (r14 proven) --
__global__ __launch_bounds__(256) void proj_kernel(
    const unsigned short* __restrict__ AQ,
    const unsigned short* __restrict__ WT,
    const float* __restrict__ bias,
    float* __restrict__ Out)
{
  __shared__ __align__(16) unsigned short As[2][128 * 32];
  __shared__ __align__(16) unsigned short Bs[2][64 * 32];

  const int tid = threadIdx.x;
  const int w = tid >> 6, lane = tid & 63, quad = lane >> 4, l15 = lane & 15;
  const int mh = w & 1, nh = w >> 1;
  const int n0 = blockIdx.x * 64, m0 = blockIdx.y * 128;

  f32x4 acc[4][2];
#pragma unroll
  for (int i = 0; i < 4; i++)
#pragma unroll
    for (int j = 0; j < 2; j++) acc[i][j] = (f32x4){0.f, 0.f, 0.f, 0.f};

  const int srA = tid >> 1, shA = (tid & 1) * 16;
  const int srB = tid >> 2, shB = (tid & 3) * 8;
  const int m = m0 + srA, b = m >> 11, s = m & 2047;

  {
    const int h = shA >> 6, d = shA & 63;
    long ao = ((long)((b * 16 + h) * 2048 + s)) * 64 + d;
    *(uint4*)&As[0][srA * 32 + shA]     = *(const uint4*)&AQ[ao];
    *(uint4*)&As[0][srA * 32 + shA + 8] = *(const uint4*)&AQ[ao + 8];
    long wo = (long)(n0 + srB) * 1024 + shB;
    *(uint4*)&Bs[0][srB * 32 + shB] = *(const uint4*)&WT[wo];
  }
  __syncthreads();

  int buf = 0;
  for (int kt = 0; kt < 1024; kt += 32) {
    const int nbuf = buf ^ 1;
    const bool pf = (kt + 32) < 1024;
    uint4 av0, av1, wv0;
    if (pf) {
      const int k = kt + 32 + shA, h = k >> 6, d = k & 63;
      long ao = ((long)((b * 16 + h) * 2048 + s)) * 64 + d;
      av0 = *(const uint4*)&AQ[ao];
      av1 = *(const uint4*)&AQ[ao + 8];
      long wo = (long)(n0 + srB) * 1024 + kt + 32 + shB;
      wv0 = *(const uint4*)&WT[wo];
    }

    bf16x8 af[4], bfr[2];
#pragma unroll
    for (int mq = 0; mq < 4; mq++)
      af[mq] = *(const bf16x8*)&As[buf][(mh * 64 + mq * 16 + l15) * 32 + quad * 8];
#pragma unroll
    for (int nq = 0; nq < 2; nq++)
      bfr[nq] = *(const bf16x8*)&Bs[buf][(nh * 32 + nq * 16 + l15) * 32 + quad * 8];
#pragma unroll
    for (int mq = 0; mq < 4; mq++)
#pragma unroll
      for (int nq = 0; nq < 2; nq++)
        acc[mq][nq] = __builtin_amdgcn_mfma_f32_16x16x32_bf16(af[mq], bfr[nq], acc[mq][nq], 0, 0, 0);

    if (pf) {
      *(uint4*)&As[nbuf][srA * 32 + shA]     = av0;
      *(uint4*)&As[nbuf][srA * 32 + shA + 8] = av1;
      *(uint4*)&Bs[nbuf][srB * 32 + shB]     = wv0;
    }
    __syncthreads();
    buf = nbuf;
  }

#pragma unroll
  for (int nq = 0; nq < 2; nq++) {
    int n = n0 + nh * 32 + nq * 16 + l15;
    float bv = bias[n];
#pragma unroll
    for (int mq = 0; mq < 4; mq++)
#pragma unroll
      for (int rr = 0; rr < 4; rr++) {
        int mm = m0 + mh * 64 + mq * 16 + quad * 4 + rr;
        Out[(long)mm * 1024 + n] = acc[mq][nq][rr] + bv;
      }
  }
}

extern "C" void kernel_launch(void* const* d_in, const int* in_sizes, int n_in,
                              void* d_out, int out_size, void* d_ws, size_t ws_size,
                              hipStream_t stream) {
  const float* X  = (const float*)d_in[0];
  const float* Wa = (const float*)d_in[1];
  const float* ba = (const float*)d_in[2];
  const float* Wp = (const float*)d_in[3];
  const float* bp = (const float*)d_in[4];
  const float* qg = (const float*)d_in[5];
  const float* qb = (const float*)d_in[6];
  const float* kg = (const float*)d_in[7];
  const float* kb = (const float*)d_in[8];

  const long per = 2L * 16 * 2048 * 64;     // 4,194,304 shorts
  unsigned short* ws  = (unsigned short*)d_ws;
  unsigned short* Qws = ws;
  unsigned short* Kws = Qws + per;
  unsigned short* Vt  = Kws + per;          // [bh][64 d][2048 s]

  const bool big = ws_size >= (size_t)(5L * per * 2);
  unsigned short *Xbf, *WaT, *WpT;
  if (big) {
    Xbf = Vt + per;
    WaT = Xbf + per;
    WpT = WaT + 3072L * 1024;
  } else {
    Xbf = Qws;  // unused
    WaT = Vt + per;
    WpT = WaT + 3072L * 1024;
  }
  unsigned short* WvT = WaT + 2048L * 1024;   // V rows of WaT

  // prep: blocks 0..767 WaT, 768..1023 WpT, 1024..2047 X->bf16 (big only)
  prep_kernel<<<big ? 2048 : 1024, 256, 0, stream>>>(Wa, Wp, X, WaT, WpT, Xbf);
  qkv_ln_kernel<<<dim3(16, 32), 256, 0, stream>>>(X, Xbf, big ? 1 : 0, WaT, ba,
                                                  qg, qb, kg, kb, Qws, Kws);
  vt_kernel<<<dim3(32, 8, 2), 256, 0, stream>>>(X, Xbf, big ? 1 : 0, WvT, ba, Vt);
  attn_kernel<<<dim3(16, 32), 256, 0, stream>>>(Qws, Kws, Vt);
  proj_kernel<<<dim3(16, 32), 256, 0, stream>>>(Qws, WpT, bp, (float*)d_out);
}

// Round 16
// 208.310 us; speedup vs baseline: 1.1319x; 1.0022x over previous
//
#include <hip/hip_runtime.h>
#include <hip/hip_bf16.h>

typedef __bf16 bf16x8 __attribute__((ext_vector_type(8)));
typedef float f32x4 __attribute__((ext_vector_type(4)));

#define EPS 1e-5f
// 0.125 * log2(e): folded into Q via LN gamma/beta in qkv, so P = exp2(S)
#define QSCALE 0.18033688011112042f

__device__ __forceinline__ unsigned short f2bf(float f) {
  union { float f; unsigned int i; } c; c.f = f;
  unsigned int r = c.i + 0x7FFFu + ((c.i >> 16) & 1u);
  return (unsigned short)(r >> 16);
}
// truncating fp32->bf16 (for P>=0: <=1ulp, saves the rounding chain)
__device__ __forceinline__ unsigned short f2bf_t(float f) {
  union { float f; unsigned int i; } c; c.f = f;
  return (unsigned short)(c.i >> 16);
}

// ---------------- Prep: both weight transposes + optional X convert -------
__device__ __forceinline__ void transpose_tile(
    const float* __restrict__ in, unsigned short* __restrict__ out,
    int R, int C, int ct0, int rt0, unsigned short* S /*64*72*/)
{
  const int t = threadIdx.x;
  const int r = t >> 2, c4 = (t & 3) * 16;
  {
    long base = (long)(rt0 + r) * C + ct0 + c4;
    float4 a = *(const float4*)&in[base];
    float4 b = *(const float4*)&in[base + 4];
    float4 c = *(const float4*)&in[base + 8];
    float4 d = *(const float4*)&in[base + 12];
    unsigned short v[16] = {f2bf(a.x), f2bf(a.y), f2bf(a.z), f2bf(a.w),
                            f2bf(b.x), f2bf(b.y), f2bf(b.z), f2bf(b.w),
                            f2bf(c.x), f2bf(c.y), f2bf(c.z), f2bf(c.w),
                            f2bf(d.x), f2bf(d.y), f2bf(d.z), f2bf(d.w)};
    *(uint4*)&S[r * 72 + c4]     = *(uint4*)&v[0];
    *(uint4*)&S[r * 72 + c4 + 8] = *(uint4*)&v[8];
  }
  __syncthreads();
  unsigned short tmp[16];
#pragma unroll
  for (int j = 0; j < 16; j++) tmp[j] = S[(c4 + j) * 72 + r];
  *(uint4*)&out[(long)(ct0 + r) * R + rt0 + c4]     = *(uint4*)&tmp[0];
  *(uint4*)&out[(long)(ct0 + r) * R + rt0 + c4 + 8] = *(uint4*)&tmp[8];
}

__global__ __launch_bounds__(256) void prep_kernel(
    const float* __restrict__ Wa, const float* __restrict__ Wp,
    const float* __restrict__ X,
    unsigned short* __restrict__ WaT, unsigned short* __restrict__ WpT,
    unsigned short* __restrict__ Xbf)
{
  __shared__ __align__(16) unsigned short S[64 * 72];
  const int id = blockIdx.x;
  if (id < 768) {                    // Wa [1024,3072] -> WaT [3072,1024]
    transpose_tile(Wa, WaT, 1024, 3072, (id % 48) * 64, (id / 48) * 64, S);
  } else if (id < 1024) {            // Wp [1024,1024] -> WpT [1024,1024]
    const int i2 = id - 768;
    transpose_tile(Wp, WpT, 1024, 1024, (i2 % 16) * 64, (i2 / 16) * 64, S);
  } else {                           // X fp32 -> bf16 (big-ws only)
    long i = ((long)(id - 1024) * 256 + threadIdx.x) * 16;
    float4 a = *(const float4*)&X[i];
    float4 b = *(const float4*)&X[i + 4];
    float4 c = *(const float4*)&X[i + 8];
    float4 d = *(const float4*)&X[i + 12];
    unsigned short v[16] = {f2bf(a.x), f2bf(a.y), f2bf(a.z), f2bf(a.w),
                            f2bf(b.x), f2bf(b.y), f2bf(b.z), f2bf(b.w),
                            f2bf(c.x), f2bf(c.y), f2bf(c.z), f2bf(c.w),
                            f2bf(d.x), f2bf(d.y), f2bf(d.z), f2bf(d.w)};
    *(uint4*)&Xbf[i]     = *(uint4*)&v[0];
    *(uint4*)&Xbf[i + 8] = *(uint4*)&v[8];
  }
}

// ---------- Merged GEMM: blocks 0..511 Q/K+LN, 512..1023 V^T --------------
__global__ __launch_bounds__(256) void qkvt_kernel(
    const float* __restrict__ Xf,
    const unsigned short* __restrict__ Xbf, int use_xbf,
    const unsigned short* __restrict__ WT,    // WaT [3072,1024]
    const float* __restrict__ bias,           // b_attn [3072]
    const float* __restrict__ qg, const float* __restrict__ qb,
    const float* __restrict__ kg, const float* __restrict__ kb,
    unsigned short* __restrict__ Qws, unsigned short* __restrict__ Kws,
    unsigned short* __restrict__ Vt)
{
  __shared__ __align__(16) unsigned short As[2][128 * 32];
  __shared__ __align__(16) unsigned short Bs[2][128 * 32];

  const int tid = threadIdx.x;
  const int w = tid >> 6, lane = tid & 63, quad = lane >> 4, l15 = lane & 15;
  const int mh = w & 1, nh = w >> 1;
  const int id = blockIdx.x;

  if (id < 512) {
    // ---------------- Q/K GEMM 128x128 + QK-LN ----------------
    const int n0 = (id & 15) * 128, m0 = (id >> 4) * 128;

    f32x4 acc[4][4];
#pragma unroll
    for (int i = 0; i < 4; i++)
#pragma unroll
      for (int j = 0; j < 4; j++) acc[i][j] = (f32x4){0.f, 0.f, 0.f, 0.f};

    const int sr2 = tid >> 1, sh2 = (tid & 1) * 16;

    if (use_xbf) {
      long xo = (long)(m0 + sr2) * 1024 + sh2;
      *(uint4*)&As[0][sr2 * 32 + sh2]     = *(const uint4*)&Xbf[xo];
      *(uint4*)&As[0][sr2 * 32 + sh2 + 8] = *(const uint4*)&Xbf[xo + 8];
    } else {
      long xo = (long)(m0 + sr2) * 1024 + sh2;
      float4 a0 = *(const float4*)&Xf[xo];
      float4 a1 = *(const float4*)&Xf[xo + 4];
      float4 a2 = *(const float4*)&Xf[xo + 8];
      float4 a3 = *(const float4*)&Xf[xo + 12];
      unsigned short v[16] = {f2bf(a0.x), f2bf(a0.y), f2bf(a0.z), f2bf(a0.w),
                              f2bf(a1.x), f2bf(a1.y), f2bf(a1.z), f2bf(a1.w),
                              f2bf(a2.x), f2bf(a2.y), f2bf(a2.z), f2bf(a2.w),
                              f2bf(a3.x), f2bf(a3.y), f2bf(a3.z), f2bf(a3.w)};
      *(uint4*)&As[0][sr2 * 32 + sh2]     = *(uint4*)&v[0];
      *(uint4*)&As[0][sr2 * 32 + sh2 + 8] = *(uint4*)&v[8];
    }
    {
      long wo = (long)(n0 + sr2) * 1024 + sh2;
      *(uint4*)&Bs[0][sr2 * 32 + sh2]     = *(const uint4*)&WT[wo];
      *(uint4*)&Bs[0][sr2 * 32 + sh2 + 8] = *(const uint4*)&WT[wo + 8];
    }
    __syncthreads();

    int buf = 0;
    for (int kt = 0; kt < 1024; kt += 32) {
      const int nbuf = buf ^ 1;
      const bool pf = (kt + 32) < 1024;
      uint4 xv0, xv1, wv0, wv1;
      float4 a0, a1, a2, a3;
      if (pf) {
        if (use_xbf) {
          long xo = (long)(m0 + sr2) * 1024 + kt + 32 + sh2;
          xv0 = *(const uint4*)&Xbf[xo];
          xv1 = *(const uint4*)&Xbf[xo + 8];
        } else {
          long xo = (long)(m0 + sr2) * 1024 + kt + 32 + sh2;
          a0 = *(const float4*)&Xf[xo];
          a1 = *(const float4*)&Xf[xo + 4];
          a2 = *(const float4*)&Xf[xo + 8];
          a3 = *(const float4*)&Xf[xo + 12];
        }
        long wo = (long)(n0 + sr2) * 1024 + kt + 32 + sh2;
        wv0 = *(const uint4*)&WT[wo];
        wv1 = *(const uint4*)&WT[wo + 8];
      }

      bf16x8 af[4], bfr[4];
#pragma unroll
      for (int mq = 0; mq < 4; mq++)
        af[mq] = *(const bf16x8*)&As[buf][(mh * 64 + mq * 16 + l15) * 32 + quad * 8];
#pragma unroll
      for (int nq = 0; nq < 4; nq++)
        bfr[nq] = *(const bf16x8*)&Bs[buf][(nh * 64 + nq * 16 + l15) * 32 + quad * 8];
#pragma unroll
      for (int mq = 0; mq < 4; mq++)
#pragma unroll
        for (int nq = 0; nq < 4; nq++)
          acc[mq][nq] = __builtin_amdgcn_mfma_f32_16x16x32_bf16(af[mq], bfr[nq], acc[mq][nq], 0, 0, 0);

      if (pf) {
        if (use_xbf) {
          *(uint4*)&As[nbuf][sr2 * 32 + sh2]     = xv0;
          *(uint4*)&As[nbuf][sr2 * 32 + sh2 + 8] = xv1;
        } else {
          unsigned short v[16] = {f2bf(a0.x), f2bf(a0.y), f2bf(a0.z), f2bf(a0.w),
                                  f2bf(a1.x), f2bf(a1.y), f2bf(a1.z), f2bf(a1.w),
                                  f2bf(a2.x), f2bf(a2.y), f2bf(a2.z), f2bf(a2.w),
                                  f2bf(a3.x), f2bf(a3.y), f2bf(a3.z), f2bf(a3.w)};
          *(uint4*)&As[nbuf][sr2 * 32 + sh2]     = *(uint4*)&v[0];
          *(uint4*)&As[nbuf][sr2 * 32 + sh2 + 8] = *(uint4*)&v[8];
        }
        *(uint4*)&Bs[nbuf][sr2 * 32 + sh2]     = wv0;
        *(uint4*)&Bs[nbuf][sr2 * 32 + sh2 + 8] = wv1;
      }
      __syncthreads();
      buf = nbuf;
    }

#pragma unroll
    for (int nq = 0; nq < 4; nq++) {
      float bv = bias[n0 + nh * 64 + nq * 16 + l15];
#pragma unroll
      for (int mq = 0; mq < 4; mq++)
#pragma unroll
        for (int rr = 0; rr < 4; rr++) acc[mq][nq][rr] += bv;
    }

    const int g = (n0 >> 6) + nh;   // 0..31: Q heads then K heads
    const bool isQ = g < 16;
    {
      float gv[4], bev[4];
#pragma unroll
      for (int nq = 0; nq < 4; nq++) {
        int d = nq * 16 + l15;
        gv[nq]  = isQ ? qg[d] : kg[d];
        bev[nq] = isQ ? qb[d] : kb[d];
        if (isQ) { gv[nq] *= QSCALE; bev[nq] *= QSCALE; }
      }
#pragma unroll
      for (int mq = 0; mq < 4; mq++)
#pragma unroll
        for (int rr = 0; rr < 4; rr++) {
          float s  = acc[mq][0][rr] + acc[mq][1][rr] + acc[mq][2][rr] + acc[mq][3][rr];
          float s2 = acc[mq][0][rr]*acc[mq][0][rr] + acc[mq][1][rr]*acc[mq][1][rr]
                   + acc[mq][2][rr]*acc[mq][2][rr] + acc[mq][3][rr]*acc[mq][3][rr];
#pragma unroll
          for (int off = 1; off < 16; off <<= 1) {
            s  += __shfl_xor(s,  off, 64);
            s2 += __shfl_xor(s2, off, 64);
          }
          float mu   = s * (1.0f / 64.0f);
          float var  = fmaxf(s2 * (1.0f / 64.0f) - mu * mu, 0.f);
          float rstd = rsqrtf(var + EPS);
#pragma unroll
          for (int nq = 0; nq < 4; nq++)
            acc[mq][nq][rr] = (acc[mq][nq][rr] - mu) * rstd * gv[nq] + bev[nq];
        }
    }

    unsigned short* dst = isQ ? Qws : Kws;
    const int head = isQ ? g : g - 16;
#pragma unroll
    for (int mq = 0; mq < 4; mq++)
#pragma unroll
      for (int rr = 0; rr < 4; rr++) {
        int m = m0 + mh * 64 + mq * 16 + quad * 4 + rr;
        int b = m >> 11, s = m & 2047;
        long base = ((long)((b * 16 + head) * 2048 + s)) * 64;
#pragma unroll
        for (int nq = 0; nq < 4; nq++)
          dst[base + nq * 16 + l15] = f2bf(acc[mq][nq][rr]);
      }
  } else {
    // ---------------- V^T GEMM 128x64: Vt[bh][d][s] ----------------
    const int id2 = id - 512;
    const int n0 = (id2 & 31) * 64, m0 = ((id2 >> 5) & 7) * 128, bz = id2 >> 8;
    const long xrow0 = (long)bz * 2048;
    const unsigned short* WvT = WT + 2048L * 1024;

    f32x4 acc[4][2];
#pragma unroll
    for (int i = 0; i < 4; i++)
#pragma unroll
      for (int j = 0; j < 2; j++) acc[i][j] = (f32x4){0.f, 0.f, 0.f, 0.f};

    const int srA = tid >> 1, shA = (tid & 1) * 16;
    const int srB = tid >> 2, shB = (tid & 3) * 8;

    {
      long wo = (long)(m0 + srA) * 1024 + shA;
      *(uint4*)&As[0][srA * 32 + shA]     = *(const uint4*)&WvT[wo];
      *(uint4*)&As[0][srA * 32 + shA + 8] = *(const uint4*)&WvT[wo + 8];
    }
    if (use_xbf) {
      long xo = (xrow0 + n0 + srB) * 1024 + shB;
      *(uint4*)&Bs[0][srB * 32 + shB] = *(const uint4*)&Xbf[xo];
    } else {
      long xo = (xrow0 + n0 + srB) * 1024 + shB;
      float4 a0 = *(const float4*)&Xf[xo];
      float4 a1 = *(const float4*)&Xf[xo + 4];
      unsigned short v[8] = {f2bf(a0.x), f2bf(a0.y), f2bf(a0.z), f2bf(a0.w),
                             f2bf(a1.x), f2bf(a1.y), f2bf(a1.z), f2bf(a1.w)};
      *(uint4*)&Bs[0][srB * 32 + shB] = *(uint4*)v;
    }
    __syncthreads();

    int buf = 0;
    for (int kt = 0; kt < 1024; kt += 32) {
      const int nbuf = buf ^ 1;
      const bool pf = (kt + 32) < 1024;
      uint4 wv0, wv1, xv0;
      float4 a0, a1;
      if (pf) {
        long wo = (long)(m0 + srA) * 1024 + kt + 32 + shA;
        wv0 = *(const uint4*)&WvT[wo];
        wv1 = *(const uint4*)&WvT[wo + 8];
        long xo = (xrow0 + n0 + srB) * 1024 + kt + 32 + shB;
        if (use_xbf) {
          xv0 = *(const uint4*)&Xbf[xo];
        } else {
          a0 = *(const float4*)&Xf[xo];
          a1 = *(const float4*)&Xf[xo + 4];
        }
      }

      bf16x8 af[4], bfr[2];
#pragma unroll
      for (int mq = 0; mq < 4; mq++)
        af[mq] = *(const bf16x8*)&As[buf][(mh * 64 + mq * 16 + l15) * 32 + quad * 8];
#pragma unroll
      for (int nq = 0; nq < 2; nq++)
        bfr[nq] = *(const bf16x8*)&Bs[buf][(nh * 32 + nq * 16 + l15) * 32 + quad * 8];
#pragma unroll
      for (int mq = 0; mq < 4; mq++)
#pragma unroll
        for (int nq = 0; nq < 2; nq++)
          acc[mq][nq] = __builtin_amdgcn_mfma_f32_16x16x32_bf16(af[mq], bfr[nq], acc[mq][nq], 0, 0, 0);

      if (pf) {
        *(uint4*)&As[nbuf][srA * 32 + shA]     = wv0;
        *(uint4*)&As[nbuf][srA * 32 + shA + 8] = wv1;
        if (use_xbf) {
          *(uint4*)&Bs[nbuf][srB * 32 + shB] = xv0;
        } else {
          unsigned short v[8] = {f2bf(a0.x), f2bf(a0.y), f2bf(a0.z), f2bf(a0.w),
                                 f2bf(a1.x), f2bf(a1.y), f2bf(a1.z), f2bf(a1.w)};
          *(uint4*)&Bs[nbuf][srB * 32 + shB] = *(uint4*)v;
        }
      }
      __syncthreads();
      buf = nbuf;
    }

    const long outb = (long)bz * 2097152;
#pragma unroll
    for (int mq = 0; mq < 4; mq++)
#pragma unroll
      for (int rr = 0; rr < 4; rr++) {
        int m = m0 + mh * 64 + mq * 16 + quad * 4 + rr;
        float bv = bias[2048 + m];
#pragma unroll
        for (int nq = 0; nq < 2; nq++) {
          int n = n0 + nh * 32 + nq * 16 + l15;
          Vt[outb + (long)m * 2048 + n] = f2bf(acc[mq][nq][rr] + bv);
        }
      }
  }
}

// ---------------- Kernel 2: causal attention, XCD-local bh ----------------
// Uniform 33-unit blocks (q-tile pair {x,31-x}). 1D grid 512; id%8 = XCD
// (dispatch heuristic): bh = (id&7)*4 + ((id>>3)&3) keeps each bh's K/Vt
// (512 KB) on one XCD's L2 (4 bh x 512 KB = 2 MB < 4 MB).
__global__ __launch_bounds__(256) void attn_kernel(
    unsigned short* __restrict__ Qws,        // in: Q (pre-scaled), out: O
    const unsigned short* __restrict__ Kws,
    const unsigned short* __restrict__ Vt)
{
  __shared__ __align__(16) unsigned short Ks[64 * 72];
  __shared__ __align__(16) unsigned short VTs[64 * 72];  // [d][s-kb]
  __shared__ __align__(16) unsigned short Ps[64 * 64];   // swizzled; Q staging

  const int tid = threadIdx.x;
  const int w = tid >> 6, lane = tid & 63, quad = lane >> 4, l15 = lane & 15;
  const int id = blockIdx.x;
  const int bh = (id & 7) * 4 + ((id >> 3) & 3);
  const int x  = id >> 5;                    // 0..15
  const long bhoff = (long)bh * 2048 * 64;
  const long bhv   = (long)bh * 131072;      // 64*2048

  const int sr = tid >> 2, sc = (tid & 3) * 16;
  const int qsw = ((sr >> 2) & 3) << 4;
  const int sw = ((l15 >> 2) & 3) << 4;
  const int pc0 = (quad * 8) ^ sw;
  const int pc1 = (32 + quad * 8) ^ sw;

  bf16x8 ones;
  {
    union { unsigned short u[8]; bf16x8 v; } c;
#pragma unroll
    for (int i = 0; i < 8; i++) c.u[i] = 0x3F80u;
    ones = c.v;
  }

#pragma unroll
  for (int ph = 0; ph < 2; ph++) {
    const int qt = ph ? (31 - x) : x;
    const int qbase = qt * 64;
    const int jmax = qt + 1;

    if (ph) __syncthreads();

    *(uint4*)&Ps[sr * 64 + (sc ^ qsw)]       = *(const uint4*)&Qws[bhoff + (qbase + sr) * 64 + sc];
    *(uint4*)&Ps[sr * 64 + ((sc ^ qsw) + 8)] = *(const uint4*)&Qws[bhoff + (qbase + sr) * 64 + sc + 8];
    *(uint4*)&Ks[sr * 72 + sc]      = *(const uint4*)&Kws[bhoff + sr * 64 + sc];
    *(uint4*)&Ks[sr * 72 + sc + 8]  = *(const uint4*)&Kws[bhoff + sr * 64 + sc + 8];
    *(uint4*)&VTs[sr * 72 + sc]     = *(const uint4*)&Vt[bhv + sr * 2048 + sc];
    *(uint4*)&VTs[sr * 72 + sc + 8] = *(const uint4*)&Vt[bhv + sr * 2048 + sc + 8];
    __syncthreads();

    const bf16x8 qf0 = *(const bf16x8*)&Ps[(w * 16 + l15) * 64 + pc0];
    const bf16x8 qf1 = *(const bf16x8*)&Ps[(w * 16 + l15) * 64 + pc1];

    f32x4 o[4], osum;
#pragma unroll
    for (int i = 0; i < 4; i++) o[i] = (f32x4){0.f, 0.f, 0.f, 0.f};
    osum = (f32x4){0.f, 0.f, 0.f, 0.f};

    for (int j = 0; j < jmax; j++) {
      const int kb = j * 64;
      const bool pf = (j + 1) < jmax;
      uint4 pk0, pk1, pv0, pv1;
      if (pf) {
        const int kb1 = kb + 64;
        pk0 = *(const uint4*)&Kws[bhoff + (kb1 + sr) * 64 + sc];
        pk1 = *(const uint4*)&Kws[bhoff + (kb1 + sr) * 64 + sc + 8];
        pv0 = *(const uint4*)&Vt[bhv + sr * 2048 + kb1 + sc];
        pv1 = *(const uint4*)&Vt[bhv + sr * 2048 + kb1 + sc + 8];
      }

      f32x4 sacc[4];
#pragma unroll
      for (int i = 0; i < 4; i++) sacc[i] = (f32x4){0.f, 0.f, 0.f, 0.f};
#pragma unroll
      for (int nt = 0; nt < 4; nt++) {
        bf16x8 kf0 = *(const bf16x8*)&Ks[(nt * 16 + l15) * 72 + quad * 8];
        bf16x8 kf1 = *(const bf16x8*)&Ks[(nt * 16 + l15) * 72 + 32 + quad * 8];
        sacc[nt] = __builtin_amdgcn_mfma_f32_16x16x32_bf16(qf0, kf0, sacc[nt], 0, 0, 0);
        sacc[nt] = __builtin_amdgcn_mfma_f32_16x16x32_bf16(qf1, kf1, sacc[nt], 0, 0, 0);
      }

      const bool domask = (j == qt);
#pragma unroll
      for (int nt = 0; nt < 4; nt++)
#pragma unroll
        for (int rr = 0; rr < 4; rr++) {
          float p = exp2f(sacc[nt][rr]);
          if (domask) {
            int kcol = kb + nt * 16 + l15;
            int qrow = qbase + w * 16 + quad * 4 + rr;
            if (kcol > qrow) p = 0.f;
          }
          sacc[nt][rr] = p;
        }

#pragma unroll
      for (int rr = 0; rr < 4; rr++)
#pragma unroll
        for (int nt = 0; nt < 4; nt++)
          Ps[(w * 16 + quad * 4 + rr) * 64 + (((nt ^ quad) & 3) * 16 + l15)]
              = f2bf_t(sacc[nt][rr]);

      bf16x8 pfr0 = *(const bf16x8*)&Ps[(w * 16 + l15) * 64 + pc0];
      bf16x8 pfr1 = *(const bf16x8*)&Ps[(w * 16 + l15) * 64 + pc1];

      osum = __builtin_amdgcn_mfma_f32_16x16x32_bf16(pfr0, ones, osum, 0, 0, 0);
      osum = __builtin_amdgcn_mfma_f32_16x16x32_bf16(pfr1, ones, osum, 0, 0, 0);
#pragma unroll
      for (int dt = 0; dt < 4; dt++) {
        bf16x8 vf0 = *(const bf16x8*)&VTs[(dt * 16 + l15) * 72 + quad * 8];
        bf16x8 vf1 = *(const bf16x8*)&VTs[(dt * 16 + l15) * 72 + 32 + quad * 8];
        o[dt] = __builtin_amdgcn_mfma_f32_16x16x32_bf16(pfr0, vf0, o[dt], 0, 0, 0);
        o[dt] = __builtin_amdgcn_mfma_f32_16x16x32_bf16(pfr1, vf1, o[dt], 0, 0, 0);
      }

      if (pf) {
        __syncthreads();
        *(uint4*)&Ks[sr * 72 + sc]      = pk0;
        *(uint4*)&Ks[sr * 72 + sc + 8]  = pk1;
        *(uint4*)&VTs[sr * 72 + sc]     = pv0;
        *(uint4*)&VTs[sr * 72 + sc + 8] = pv1;
        __syncthreads();
      }
    }

#pragma unroll
    for (int rr = 0; rr < 4; rr++) {
      float inv = 1.0f / osum[rr];
      int row = qbase + w * 16 + quad * 4 + rr;
      long base = bhoff + (long)row * 64;
#pragma unroll
      for (int dt = 0; dt < 4; dt++)
        Qws[base + dt * 16 + l15] = f2bf(o[dt][rr] * inv);
    }
  }
}

// ---------------- Kernel 3: output projection, 128x64 tiles (r14 proven) --
__global__ __launch_bounds__(256) void proj_kernel(
    const unsigned short* __restrict__ AQ,
    const unsigned short* __restrict__ WT,
    const float* __restrict__ bias,
    float* __restrict__ Out)
{
  __shared__ __align__(16) unsigned short As[2][128 * 32];
  __shared__ __align__(16) unsigned short Bs[2][64 * 32];

  const int tid = threadIdx.x;
  const int w = tid >> 6, lane = tid & 63, quad = lane >> 4, l15 = lane & 15;
  const int mh = w & 1, nh = w >> 1;
  const int n0 = blockIdx.x * 64, m0 = blockIdx.y * 128;

  f32x4 acc[4][2];
#pragma unroll
  for (int i = 0; i < 4; i++)
#pragma unroll
    for (int j = 0; j < 2; j++) acc[i][j] = (f32x4){0.f, 0.f, 0.f, 0.f};

  const int srA = tid >> 1, shA = (tid & 1) * 16;
  const int srB = tid >> 2, shB = (tid & 3) * 8;
  const int m = m0 + srA, b = m >> 11, s = m & 2047;

  {
    const int h = shA >> 6, d = shA & 63;
    long ao = ((long)((b * 16 + h) * 2048 + s)) * 64 + d;
    *(uint4*)&As[0][srA * 32 + shA]     = *(const uint4*)&AQ[ao];
    *(uint4*)&As[0][srA * 32 + shA + 8] = *(const uint4*)&AQ[ao + 8];
    long wo = (long)(n0 + srB) * 1024 + shB;
    *(uint4*)&Bs[0][srB * 32 + shB] = *(const uint4*)&WT[wo];
  }
  __syncthreads();

  int buf = 0;
  for (int kt = 0; kt < 1024; kt += 32) {
    const int nbuf = buf ^ 1;
    const bool pf = (kt + 32) < 1024;
    uint4 av0, av1, wv0;
    if (pf) {
      const int k = kt + 32 + shA, h = k >> 6, d = k & 63;
      long ao = ((long)((b * 16 + h) * 2048 + s)) * 64 + d;
      av0 = *(const uint4*)&AQ[ao];
      av1 = *(const uint4*)&AQ[ao + 8];
      long wo = (long)(n0 + srB) * 1024 + kt + 32 + shB;
      wv0 = *(const uint4*)&WT[wo];
    }

    bf16x8 af[4], bfr[2];
#pragma unroll
    for (int mq = 0; mq < 4; mq++)
      af[mq] = *(const bf16x8*)&As[buf][(mh * 64 + mq * 16 + l15) * 32 + quad * 8];
#pragma unroll
    for (int nq = 0; nq < 2; nq++)
      bfr[nq] = *(const bf16x8*)&Bs[buf][(nh * 32 + nq * 16 + l15) * 32 + quad * 8];
#pragma unroll
    for (int mq = 0; mq < 4; mq++)
#pragma unroll
      for (int nq = 0; nq < 2; nq++)
        acc[mq][nq] = __builtin_amdgcn_mfma_f32_16x16x32_bf16(af[mq], bfr[nq], acc[mq][nq], 0, 0, 0);

    if (pf) {
      *(uint4*)&As[nbuf][srA * 32 + shA]     = av0;
      *(uint4*)&As[nbuf][srA * 32 + shA + 8] = av1;
      *(uint4*)&Bs[nbuf][srB * 32 + shB]     = wv0;
    }
    __syncthreads();
    buf = nbuf;
  }

#pragma unroll
  for (int nq = 0; nq < 2; nq++) {
    int n = n0 + nh * 32 + nq * 16 + l15;
    float bv = bias[n];
#pragma unroll
    for (int mq = 0; mq < 4; mq++)
#pragma unroll
      for (int rr = 0; rr < 4; rr++) {
        int mm = m0 + mh * 64 + mq * 16 + quad * 4 + rr;
        Out[(long)mm * 1024 + n] = acc[mq][nq][rr] + bv;
      }
  }
}

extern "C" void kernel_launch(void* const* d_in, const int* in_sizes, int n_in,
                              void* d_out, int out_size, void* d_ws, size_t ws_size,
                              hipStream_t stream) {
  const float* X  = (const float*)d_in[0];
  const float* Wa = (const float*)d_in[1];
  const float* ba = (const float*)d_in[2];
  const float* Wp = (const float*)d_in[3];
  const float* bp = (const float*)d_in[4];
  const float* qg = (const float*)d_in[5];
  const float* qb = (const float*)d_in[6];
  const float* kg = (const float*)d_in[7];
  const float* kb = (const float*)d_in[8];

  const long per = 2L * 16 * 2048 * 64;     // 4,194,304 shorts
  unsigned short* ws  = (unsigned short*)d_ws;
  unsigned short* Qws = ws;
  unsigned short* Kws = Qws + per;
  unsigned short* Vt  = Kws + per;          // [bh][64 d][2048 s]

  const bool big = ws_size >= (size_t)(5L * per * 2);
  unsigned short *Xbf, *WaT, *WpT;
  if (big) {
    Xbf = Vt + per;
    WaT = Xbf + per;
    WpT = WaT + 3072L * 1024;
  } else {
    Xbf = Qws;  // unused
    WaT = Vt + per;
    WpT = WaT + 3072L * 1024;
  }

  prep_kernel<<<big ? 2048 : 1024, 256, 0, stream>>>(Wa, Wp, X, WaT, WpT, Xbf);
  qkvt_kernel<<<1024, 256, 0, stream>>>(X, Xbf, big ? 1 : 0, WaT, ba,
                                        qg, qb, kg, kb, Qws, Kws, Vt);
  attn_kernel<<<512, 256, 0, stream>>>(Qws, Kws, Vt);
  proj_kernel<<<dim3(16, 32), 256, 0, stream>>>(Qws, WpT, bp, (float*)d_out);
}